// Round 5
// baseline (320.890 us; speedup 1.0000x reference)
//
#include <hip/hip_runtime.h>
#include <stdint.h>

#define NEG_SLOPE 0.2f
#define EPSV 1e-16f
#define NBLK 256   // scatter/histogram blocks (fixed, deterministic edge ranges)

typedef __attribute__((ext_vector_type(8))) short short8;
typedef __attribute__((ext_vector_type(4))) float f32x4;

// round-to-nearest-even fp32 -> bf16 bits
__device__ inline short bf16r(float f){
  union { float f; unsigned u; } v; v.f = f;
  unsigned r = (v.u + 0x7FFFu + ((v.u >> 16) & 1u)) >> 16;
  return (short)r;
}
__device__ inline float bf16lo(unsigned u){  // low bf16 of a packed pair (or zero-ext ushort)
  union { unsigned u; float f; } v; v.u = u << 16; return v.f;
}
__device__ inline float bf16hi(unsigned u){  // high bf16 of a packed pair
  union { unsigned u; float f; } v; v.u = u & 0xFFFF0000u; return v.f;
}

// ---------------- edge access (int32 or int64 edge_index, [2,E] row-major) ----------------
__device__ inline void get_edge(const void* ei, int is64, int E, int e, int& s, int& d){
  if (e >= E){ s = d = e - E; return; }  // self loops appended
  if (is64){
    const long long* p = (const long long*)ei;
    s = (int)p[e]; d = (int)p[(long long)E + e];
  } else {
    const int* p = (const int*)ei;
    s = p[e]; d = p[E + e];
  }
}

__device__ inline int get_dst(const void* ei, int is64, int E, int e){
  if (e >= E) return e - E;
  if (is64) return (int)((const long long*)ei)[(long long)E + e];
  return ((const int*)ei)[E + e];
}

__global__ void detect_dtype(const int* ei32, int* flag){
  if (threadIdx.x == 0 && blockIdx.x == 0){
    int nz = 0;
    for (int i = 0; i < 64; ++i) nz |= ei32[2*i + 1];  // int64: high words all 0
    *flag = (nz == 0) ? 1 : 0;
  }
}

// ---------------- fp32 -> bf16 conversion (vectorized: 4 elems/thread) ----------------
__global__ void cvt_to_bf16(const float* __restrict__ x, short* __restrict__ xb, int n4){
  int i = blockIdx.x*blockDim.x + threadIdx.x;
  if (i >= n4) return;
  f32x4 v = *(const f32x4*)(x + (size_t)i*4);
  short4 o;
  o.x = bf16r(v[0]); o.y = bf16r(v[1]); o.z = bf16r(v[2]); o.w = bf16r(v[3]);
  *(short4*)(xb + (size_t)i*4) = o;
}

// ---------------- pack W [K x NCOL] row-major fp32 -> per-fragment bf16 layout ----------------
__global__ void pack_w(const float* __restrict__ W, short* __restrict__ Wp, int K, int NCOL){
  int NNT = NCOL >> 4;
  int total = K*NCOL;
  int idx = blockIdx.x*blockDim.x + threadIdx.x;
  if (idx >= total) return;
  int j = idx & 7, n16 = (idx >> 3) & 15, q = (idx >> 7) & 3, tile = idx >> 9;
  int nt = tile % NNT, kt = tile / NNT;
  int k = kt*32 + q*8 + j, n = nt*16 + n16;
  Wp[idx] = bf16r(W[k*NCOL + n]);
}

// ---------------- MFMA GEMM: Cb (bf16 out only) ----------------
template<int K, int NCOL>
__global__ __launch_bounds__(256) void gemm_mfma(const short* __restrict__ A, const short* __restrict__ Bp,
                                                 short* __restrict__ Cb, int M){
  constexpr int NKT = K/32, NNT = NCOL/16;
  int wave = (blockIdx.x*256 + (int)threadIdx.x) >> 6;
  int lane = threadIdx.x & 63;
  int row0 = wave << 4;
  if (row0 >= M) return;
  int m = lane & 15, q = lane >> 4;
  f32x4 acc[NNT];
#pragma unroll
  for (int i = 0; i < NNT; ++i) acc[i] = (f32x4){0.f,0.f,0.f,0.f};
#pragma unroll
  for (int kt = 0; kt < NKT; ++kt){
    short8 a = *(const short8*)(A + (size_t)(row0 + m)*K + kt*32 + q*8);
#pragma unroll
    for (int nt = 0; nt < NNT; ++nt){
      short8 b = *(const short8*)(Bp + (size_t)(((kt*NNT + nt)*4 + q)*16 + m)*8);
      acc[nt] = __builtin_amdgcn_mfma_f32_16x16x32_bf16(a, b, acc[nt], 0, 0, 0);
    }
  }
#pragma unroll
  for (int nt = 0; nt < NNT; ++nt){
#pragma unroll
    for (int r = 0; r < 4; ++r){
      Cb[(size_t)(row0 + q*4 + r)*NCOL + nt*16 + m] = bf16r(acc[nt][r]);
    }
  }
}

// ---------------- attention logit reductions (from bf16 h) ----------------
__global__ void logits_l1(const unsigned short* __restrict__ h1b, const float* __restrict__ att_s,
                          const float* __restrict__ att_d, float* __restrict__ asrc,
                          float* __restrict__ adst, int N){
  int tid = threadIdx.x;
  int n = blockIdx.x*4 + (tid >> 6);
  int j = tid & 63;
  if (n >= N) return;
  float h = bf16lo((unsigned)h1b[(size_t)n*64 + j]);
  float ps = h * att_s[j];
  float pd = h * att_d[j];
#pragma unroll
  for (int mm = 4; mm; mm >>= 1){ ps += __shfl_xor(ps, mm, 8); pd += __shfl_xor(pd, mm, 8); }
  if ((j & 7) == 0){ asrc[n*8 + (j >> 3)] = ps; adst[n*8 + (j >> 3)] = pd; }
}

__global__ void logits_l2(const unsigned* __restrict__ h2u, const float* __restrict__ att_s,
                          const float* __restrict__ att_d, float* __restrict__ asrc,
                          float* __restrict__ adst, int N){
  int tid = threadIdx.x;
  int n = blockIdx.x*4 + (tid >> 6);
  int l = tid & 63;
  if (n >= N) return;
  unsigned u = h2u[(size_t)n*64 + l];
  float x0 = bf16lo(u), x1 = bf16hi(u);
  float ps = x0*att_s[2*l] + x1*att_s[2*l + 1];
  float pd = x0*att_d[2*l] + x1*att_d[2*l + 1];
#pragma unroll
  for (int mm = 32; mm; mm >>= 1){ ps += __shfl_xor(ps, mm, 64); pd += __shfl_xor(pd, mm, 64); }
  if (l == 0){ asrc[n] = ps; adst[n] = pd; }
}

// ================= CSR build: two-level counting sort (no global atomics) =================
__global__ __launch_bounds__(256) void p1_hist(const void* ei, const int* flag, int E, int E2,
                                               int* __restrict__ block_counts){
  __shared__ int h[256];
  int t = threadIdx.x, blk = blockIdx.x;
  h[t] = 0; __syncthreads();
  int chunk = (E2 + NBLK - 1)/NBLK;
  int beg = blk*chunk, end = min(beg + chunk, E2);
  int is64 = *flag;
  for (int e = beg + t; e < end; e += 256){
    int d = get_dst(ei, is64, E, e);
    atomicAdd(&h[d >> 8], 1);
  }
  __syncthreads();
  block_counts[blk*256 + t] = h[t];
}

__global__ void p2_bucket_scan(const int* __restrict__ block_counts, int* __restrict__ bucket_base){
  __shared__ int sd[256];
  int t = threadIdx.x;
  int tot = 0;
  for (int b = 0; b < NBLK; ++b) tot += block_counts[b*256 + t];
  sd[t] = tot; __syncthreads();
  for (int off = 1; off < 256; off <<= 1){
    int v = (t >= off) ? sd[t - off] : 0;
    __syncthreads(); sd[t] += v; __syncthreads();
  }
  bucket_base[t] = sd[t] - tot;            // exclusive
  if (t == 255) bucket_base[256] = sd[255];
}

__global__ void p2_block_off(const int* __restrict__ block_counts, const int* __restrict__ bucket_base,
                             int* __restrict__ block_off){
  __shared__ int sd[256];
  int b = blockIdx.x, t = threadIdx.x;
  int v = block_counts[t*256 + b];
  sd[t] = v; __syncthreads();
  for (int off = 1; off < 256; off <<= 1){
    int u = (t >= off) ? sd[t - off] : 0;
    __syncthreads(); sd[t] += u; __syncthreads();
  }
  block_off[t*256 + b] = bucket_base[b] + sd[t] - v;
}

__global__ __launch_bounds__(256) void p3_scatter(const void* ei, const int* flag, int E, int E2,
                                                  const int* __restrict__ block_off,
                                                  int2* __restrict__ pairs){
  __shared__ int cur[256];
  int t = threadIdx.x, blk = blockIdx.x;
  cur[t] = block_off[blk*256 + t];
  __syncthreads();
  int chunk = (E2 + NBLK - 1)/NBLK;
  int beg = blk*chunk, end = min(beg + chunk, E2);
  int is64 = *flag;
  for (int e = beg + t; e < end; e += 256){
    int s, d; get_edge(ei, is64, E, e, s, d);
    int pos = atomicAdd(&cur[d >> 8], 1);
    pairs[pos] = make_int2(s, d);
  }
}

__global__ __launch_bounds__(256) void p4_sort(const int2* __restrict__ pairs,
                                               const int* __restrict__ bucket_base,
                                               int N, int E2,
                                               int* __restrict__ offs, int* __restrict__ srcs,
                                               int* __restrict__ dsts){
  __shared__ int hist[256];
  __shared__ int cur[256];
  int b = blockIdx.x, t = threadIdx.x;
  int base = bucket_base[b], cnt = bucket_base[b + 1] - base;
  hist[t] = 0; __syncthreads();
  for (int p = t; p < cnt; p += 256){
    int2 sd2 = pairs[base + p];
    atomicAdd(&hist[sd2.y & 255], 1);
  }
  __syncthreads();
  int v = hist[t];
  cur[t] = v; __syncthreads();
  for (int off = 1; off < 256; off <<= 1){
    int u = (t >= off) ? cur[t - off] : 0;
    __syncthreads(); cur[t] += u; __syncthreads();
  }
  int ex = cur[t] - v;   // exclusive prefix within bucket
  __syncthreads();
  cur[t] = ex;
  int node = b*256 + t;
  if (node < N) offs[node] = base + ex;
  __syncthreads();
  for (int p = t; p < cnt; p += 256){
    int2 sd2 = pairs[base + p];
    int pos = atomicAdd(&cur[sd2.y & 255], 1);
    srcs[base + pos] = sd2.x;
    dsts[base + pos] = sd2.y;
  }
  if (b == 0 && t == 0) offs[N] = E2;
}

// ================= edge-parallel weight precompute =================
// w = exp(lrelu(asrc[s] + adst[d])), computed ONCE per edge (not once per dst-wave)
__global__ __launch_bounds__(256) void wgt1(const int* __restrict__ srcs, const int* __restrict__ dsts,
                                            const float* __restrict__ asrc, const float* __restrict__ adst,
                                            short* __restrict__ w1b, int E2){
  int e = blockIdx.x*blockDim.x + threadIdx.x;
  if (e >= E2) return;
  int s = srcs[e], d = dsts[e];
  f32x4 a0 = *(const f32x4*)(asrc + (size_t)s*8);
  f32x4 a1 = *(const f32x4*)(asrc + (size_t)s*8 + 4);
  f32x4 d0 = *(const f32x4*)(adst + (size_t)d*8);
  f32x4 d1 = *(const f32x4*)(adst + (size_t)d*8 + 4);
  short8 w;
#pragma unroll
  for (int h = 0; h < 4; ++h){
    float z = a0[h] + d0[h];
    z = (z >= 0.f) ? z : NEG_SLOPE*z;
    w[h] = bf16r(__expf(z));
  }
#pragma unroll
  for (int h = 0; h < 4; ++h){
    float z = a1[h] + d1[h];
    z = (z >= 0.f) ? z : NEG_SLOPE*z;
    w[4 + h] = bf16r(__expf(z));
  }
  *(short8*)(w1b + (size_t)e*8) = w;
}

__global__ __launch_bounds__(256) void wgt2(const int* __restrict__ srcs, const int* __restrict__ dsts,
                                            const float* __restrict__ asrc, const float* __restrict__ adst,
                                            float* __restrict__ w2, int E2){
  int e = blockIdx.x*blockDim.x + threadIdx.x;
  if (e >= E2) return;
  float z = asrc[srcs[e]] + adst[dsts[e]];
  z = (z >= 0.f) ? z : NEG_SLOPE*z;
  w2[e] = __expf(z);
}

// ---------------- node-parallel aggregation (precomputed weights) ----------------
// agg_l1: lane half (lane>>5) processes edge p+half; lane owns col pair {2c,2c+1}, c=lane&31
__global__ __launch_bounds__(256) void agg_l1(const unsigned* __restrict__ h1u,
                       const unsigned short* __restrict__ w1b,
                       const int* __restrict__ offs, const int* __restrict__ srcs,
                       const float* __restrict__ bias, unsigned* __restrict__ hout, int N){
  int tid = threadIdx.x;
  int i = blockIdx.x*4 + (tid >> 6);
  if (i >= N) return;
  int lane = tid & 63;
  int half = lane >> 5, c = lane & 31, head = c >> 2;
  int beg = offs[i], end = offs[i + 1];
  float acc0 = 0.f, acc1 = 0.f, den = 0.f;
  int p = beg;
  for (; p + 8 <= end; p += 8){
    int me[4], s[4];
#pragma unroll
    for (int u = 0; u < 4; ++u) me[u] = p + 2*u + half;
#pragma unroll
    for (int u = 0; u < 4; ++u) s[u] = srcs[me[u]];
    float w[4];
#pragma unroll
    for (int u = 0; u < 4; ++u) w[u] = bf16lo((unsigned)w1b[(size_t)me[u]*8 + head]);
    unsigned v[4];
#pragma unroll
    for (int u = 0; u < 4; ++u) v[u] = h1u[(size_t)s[u]*32 + c];
#pragma unroll
    for (int u = 0; u < 4; ++u){
      den += w[u];
      acc0 = fmaf(w[u], bf16lo(v[u]), acc0);
      acc1 = fmaf(w[u], bf16hi(v[u]), acc1);
    }
  }
  for (; p + 2 <= end; p += 2){
    int me = p + half;
    int s = srcs[me];
    float w = bf16lo((unsigned)w1b[(size_t)me*8 + head]);
    unsigned v = h1u[(size_t)s*32 + c];
    den += w;
    acc0 = fmaf(w, bf16lo(v), acc0);
    acc1 = fmaf(w, bf16hi(v), acc1);
  }
  if (p < end && half == 0){
    int s = srcs[p];
    float w = bf16lo((unsigned)w1b[(size_t)p*8 + head]);
    unsigned v = h1u[(size_t)s*32 + c];
    den += w;
    acc0 = fmaf(w, bf16lo(v), acc0);
    acc1 = fmaf(w, bf16hi(v), acc1);
  }
  acc0 += __shfl_xor(acc0, 32, 64);
  acc1 += __shfl_xor(acc1, 32, 64);
  den  += __shfl_xor(den, 32, 64);
  if (half == 0){
    float inv = 1.f/(den + EPSV);
    float o0 = acc0*inv + bias[2*c];
    float o1 = acc1*inv + bias[2*c + 1];
    o0 = (o0 > 0.f) ? o0 : (__expf(o0) - 1.f);   // ELU fused
    o1 = (o1 > 0.f) ? o1 : (__expf(o1) - 1.f);
    unsigned pk = (unsigned)(unsigned short)bf16r(o0) | ((unsigned)(unsigned short)bf16r(o1) << 16);
    hout[(size_t)i*32 + c] = pk;
  }
}

// agg_l2: lane owns cols {2*lane, 2*lane+1}; weight uniform per edge
__global__ __launch_bounds__(256) void agg_l2(const unsigned* __restrict__ h2u,
                       const float* __restrict__ w2,
                       const int* __restrict__ offs, const int* __restrict__ srcs,
                       const float* __restrict__ bias, float* __restrict__ out, int N){
  int tid = threadIdx.x;
  int i = blockIdx.x*4 + (tid >> 6);
  if (i >= N) return;
  int lane = tid & 63;
  int beg = offs[i], end = offs[i + 1];
  float a0 = 0.f, a1 = 0.f, den = 0.f;
  int p = beg;
  for (; p + 8 <= end; p += 8){
    int s[8];
#pragma unroll
    for (int u = 0; u < 8; ++u) s[u] = srcs[p + u];
    float w[8];
#pragma unroll
    for (int u = 0; u < 8; ++u) w[u] = w2[p + u];
    unsigned v[8];
#pragma unroll
    for (int u = 0; u < 8; ++u) v[u] = h2u[(size_t)s[u]*64 + lane];
#pragma unroll
    for (int u = 0; u < 8; ++u){
      den += w[u];
      a0 = fmaf(w[u], bf16lo(v[u]), a0);
      a1 = fmaf(w[u], bf16hi(v[u]), a1);
    }
  }
  for (; p < end; ++p){
    int s = srcs[p];
    float w = w2[p];
    unsigned v = h2u[(size_t)s*64 + lane];
    den += w;
    a0 = fmaf(w, bf16lo(v), a0);
    a1 = fmaf(w, bf16hi(v), a1);
  }
  float inv = 1.f/(den + EPSV);
  int c0 = lane*2;
  float2 o;
  o.x = a0*inv + bias[c0];
  o.y = a1*inv + bias[c0 + 1];
  *(float2*)(out + (size_t)i*128 + c0) = o;
}

// ---------------- launch ----------------
extern "C" void kernel_launch(void* const* d_in, const int* in_sizes, int n_in,
                              void* d_out, int out_size, void* d_ws, size_t ws_size,
                              hipStream_t stream){
  const float* x   = (const float*)d_in[0];
  const void*  ei  = d_in[1];
  const float* W1  = (const float*)d_in[2];
  const float* as1 = (const float*)d_in[3];
  const float* ad1 = (const float*)d_in[4];
  const float* b1  = (const float*)d_in[5];
  const float* W2  = (const float*)d_in[6];
  const float* as2 = (const float*)d_in[7];
  const float* ad2 = (const float*)d_in[8];
  const float* b2  = (const float*)d_in[9];

  int N  = in_sizes[0] / 128;
  int E  = in_sizes[1] / 2;
  int E2 = E + N;
  int NB = (N + 255) >> 8;   // dst buckets of 256 nodes

  char* p = (char*)d_ws;
  auto alloc = [&](size_t bytes) -> void* {
    void* r = (void*)p;
    p += (bytes + 255) & ~(size_t)255;
    return r;
  };
  short* xb     = (short*)alloc((size_t)N*128*2);
  short* W1p    = (short*)alloc((size_t)128*64*2);
  short* W2p    = (short*)alloc((size_t)64*128*2);
  short* h1b    = (short*)alloc((size_t)N*64*2);
  float* asrc1  = (float*)alloc((size_t)N*8*4);
  float* adst1  = (float*)alloc((size_t)N*8*4);
  short* hin2   = (short*)alloc((size_t)N*64*2);
  short* h2b    = (short*)alloc((size_t)N*128*2);
  float* asrc2  = (float*)alloc((size_t)N*4);
  float* adst2  = (float*)alloc((size_t)N*4);
  int*   offs   = (int*)alloc((size_t)(N + 1)*4);
  int*   srcs   = (int*)alloc((size_t)E2*4);
  int*   dsts   = (int*)alloc((size_t)E2*4);
  short* w1b    = (short*)alloc((size_t)E2*8*2);   // 16 B/edge; pairs alias this pre-wgt1
  float* w2     = (float*)alloc((size_t)E2*4);
  int*   bcnt   = (int*)alloc((size_t)NBLK*256*4);
  int*   boff   = (int*)alloc((size_t)NBLK*256*4);
  int*   bbase  = (int*)alloc(257*4);
  int*   flag   = (int*)alloc(4);
  int2*  pairs  = (int2*)w1b;   // E2*8 B <= E2*16 B ✓; pairs dead before wgt1 writes w1b

  dim3 B(256);
  detect_dtype<<<1, 64, 0, stream>>>((const int*)ei, flag);

  int n4 = N*128/4;
  cvt_to_bf16<<<(n4 + 255)/256, B, 0, stream>>>(x, xb, n4);
  pack_w<<<(128*64 + 255)/256, B, 0, stream>>>(W1, W1p, 128, 64);
  pack_w<<<(64*128 + 255)/256, B, 0, stream>>>(W2, W2p, 64, 128);

  int nwav = (N + 15)/16;
  gemm_mfma<128,64><<<(nwav + 3)/4, B, 0, stream>>>(xb, W1p, h1b, N);
  logits_l1<<<(N + 3)/4, B, 0, stream>>>((const unsigned short*)h1b, as1, ad1, asrc1, adst1, N);

  // CSR by dst via two-level counting sort (reused by both layers)
  p1_hist<<<NBLK, B, 0, stream>>>(ei, flag, E, E2, bcnt);
  p2_bucket_scan<<<1, B, 0, stream>>>(bcnt, bbase);
  p2_block_off<<<256, B, 0, stream>>>(bcnt, bbase, boff);
  p3_scatter<<<NBLK, B, 0, stream>>>(ei, flag, E, E2, boff, pairs);
  p4_sort<<<NB, B, 0, stream>>>(pairs, bbase, N, E2, offs, srcs, dsts);

  int egrid = (E2 + 255)/256;
  wgt1<<<egrid, B, 0, stream>>>(srcs, dsts, asrc1, adst1, w1b, E2);
  agg_l1<<<(N + 3)/4, B, 0, stream>>>((const unsigned*)h1b, (const unsigned short*)w1b,
                                      offs, srcs, b1, (unsigned*)hin2, N);

  gemm_mfma<64,128><<<(nwav + 3)/4, B, 0, stream>>>(hin2, W2p, h2b, N);
  logits_l2<<<(N + 3)/4, B, 0, stream>>>((const unsigned*)h2b, as2, ad2, asrc2, adst2, N);
  wgt2<<<egrid, B, 0, stream>>>(srcs, dsts, asrc2, adst2, w2, E2);
  agg_l2<<<(N + 3)/4, B, 0, stream>>>((const unsigned*)h2b, w2, offs, srcs, b2, (float*)d_out, N);
}

// Round 6
// 282.685 us; speedup vs baseline: 1.1352x; 1.1352x over previous
//
#include <hip/hip_runtime.h>
#include <stdint.h>

#define NEG_SLOPE 0.2f
#define EPSV 1e-16f
#define NBLK 256   // scatter/histogram blocks (fixed, deterministic edge ranges)

typedef __attribute__((ext_vector_type(8))) short short8;
typedef __attribute__((ext_vector_type(4))) float f32x4;

// round-to-nearest-even fp32 -> bf16 bits
__device__ inline short bf16r(float f){
  union { float f; unsigned u; } v; v.f = f;
  unsigned r = (v.u + 0x7FFFu + ((v.u >> 16) & 1u)) >> 16;
  return (short)r;
}
__device__ inline float bf16lo(unsigned u){  // low bf16 of a packed pair (or zero-ext ushort)
  union { unsigned u; float f; } v; v.u = u << 16; return v.f;
}
__device__ inline float bf16hi(unsigned u){  // high bf16 of a packed pair
  union { unsigned u; float f; } v; v.u = u & 0xFFFF0000u; return v.f;
}

// ---------------- edge access (int32 or int64 edge_index, [2,E] row-major) ----------------
__device__ inline void get_edge(const void* ei, int is64, int E, int e, int& s, int& d){
  if (e >= E){ s = d = e - E; return; }  // self loops appended
  if (is64){
    const long long* p = (const long long*)ei;
    s = (int)p[e]; d = (int)p[(long long)E + e];
  } else {
    const int* p = (const int*)ei;
    s = p[e]; d = p[E + e];
  }
}

__device__ inline int get_dst(const void* ei, int is64, int E, int e){
  if (e >= E) return e - E;
  if (is64) return (int)((const long long*)ei)[(long long)E + e];
  return ((const int*)ei)[E + e];
}

__global__ void detect_dtype(const int* ei32, int* flag){
  if (threadIdx.x == 0 && blockIdx.x == 0){
    int nz = 0;
    for (int i = 0; i < 64; ++i) nz |= ei32[2*i + 1];  // int64: high words all 0
    *flag = (nz == 0) ? 1 : 0;
  }
}

// ---------------- fp32 -> bf16 conversion (vectorized: 4 elems/thread) ----------------
__global__ void cvt_to_bf16(const float* __restrict__ x, short* __restrict__ xb, int n4){
  int i = blockIdx.x*blockDim.x + threadIdx.x;
  if (i >= n4) return;
  f32x4 v = *(const f32x4*)(x + (size_t)i*4);
  short4 o;
  o.x = bf16r(v[0]); o.y = bf16r(v[1]); o.z = bf16r(v[2]); o.w = bf16r(v[3]);
  *(short4*)(xb + (size_t)i*4) = o;
}

// ---------------- pack W [K x NCOL] row-major fp32 -> per-fragment bf16 layout ----------------
__global__ void pack_w(const float* __restrict__ W, short* __restrict__ Wp, int K, int NCOL){
  int NNT = NCOL >> 4;
  int total = K*NCOL;
  int idx = blockIdx.x*blockDim.x + threadIdx.x;
  if (idx >= total) return;
  int j = idx & 7, n16 = (idx >> 3) & 15, q = (idx >> 7) & 3, tile = idx >> 9;
  int nt = tile % NNT, kt = tile / NNT;
  int k = kt*32 + q*8 + j, n = nt*16 + n16;
  Wp[idx] = bf16r(W[k*NCOL + n]);
}

// ---------------- MFMA GEMM: Cb (bf16 out only) ----------------
template<int K, int NCOL>
__global__ __launch_bounds__(256) void gemm_mfma(const short* __restrict__ A, const short* __restrict__ Bp,
                                                 short* __restrict__ Cb, int M){
  constexpr int NKT = K/32, NNT = NCOL/16;
  int wave = (blockIdx.x*256 + (int)threadIdx.x) >> 6;
  int lane = threadIdx.x & 63;
  int row0 = wave << 4;
  if (row0 >= M) return;
  int m = lane & 15, q = lane >> 4;
  f32x4 acc[NNT];
#pragma unroll
  for (int i = 0; i < NNT; ++i) acc[i] = (f32x4){0.f,0.f,0.f,0.f};
#pragma unroll
  for (int kt = 0; kt < NKT; ++kt){
    short8 a = *(const short8*)(A + (size_t)(row0 + m)*K + kt*32 + q*8);
#pragma unroll
    for (int nt = 0; nt < NNT; ++nt){
      short8 b = *(const short8*)(Bp + (size_t)(((kt*NNT + nt)*4 + q)*16 + m)*8);
      acc[nt] = __builtin_amdgcn_mfma_f32_16x16x32_bf16(a, b, acc[nt], 0, 0, 0);
    }
  }
#pragma unroll
  for (int nt = 0; nt < NNT; ++nt){
#pragma unroll
    for (int r = 0; r < 4; ++r){
      Cb[(size_t)(row0 + q*4 + r)*NCOL + nt*16 + m] = bf16r(acc[nt][r]);
    }
  }
}

// ---------------- attention logit reductions (from bf16 h) ----------------
__global__ void logits_l1(const unsigned short* __restrict__ h1b, const float* __restrict__ att_s,
                          const float* __restrict__ att_d, float* __restrict__ asrc,
                          float* __restrict__ adst, int N){
  int tid = threadIdx.x;
  int n = blockIdx.x*4 + (tid >> 6);
  int j = tid & 63;
  if (n >= N) return;
  float h = bf16lo((unsigned)h1b[(size_t)n*64 + j]);
  float ps = h * att_s[j];
  float pd = h * att_d[j];
#pragma unroll
  for (int mm = 4; mm; mm >>= 1){ ps += __shfl_xor(ps, mm, 8); pd += __shfl_xor(pd, mm, 8); }
  if ((j & 7) == 0){ asrc[n*8 + (j >> 3)] = ps; adst[n*8 + (j >> 3)] = pd; }
}

__global__ void logits_l2(const unsigned* __restrict__ h2u, const float* __restrict__ att_s,
                          const float* __restrict__ att_d, float* __restrict__ asrc,
                          float* __restrict__ adst, int N){
  int tid = threadIdx.x;
  int n = blockIdx.x*4 + (tid >> 6);
  int l = tid & 63;
  if (n >= N) return;
  unsigned u = h2u[(size_t)n*64 + l];
  float x0 = bf16lo(u), x1 = bf16hi(u);
  float ps = x0*att_s[2*l] + x1*att_s[2*l + 1];
  float pd = x0*att_d[2*l] + x1*att_d[2*l + 1];
#pragma unroll
  for (int mm = 32; mm; mm >>= 1){ ps += __shfl_xor(ps, mm, 64); pd += __shfl_xor(pd, mm, 64); }
  if (l == 0){ asrc[n] = ps; adst[n] = pd; }
}

// ================= CSR build: two-level counting sort (no global atomics) =================
__global__ __launch_bounds__(256) void p1_hist(const void* ei, const int* flag, int E, int E2,
                                               int* __restrict__ block_counts){
  __shared__ int h[256];
  int t = threadIdx.x, blk = blockIdx.x;
  h[t] = 0; __syncthreads();
  int chunk = (E2 + NBLK - 1)/NBLK;
  int beg = blk*chunk, end = min(beg + chunk, E2);
  int is64 = *flag;
  for (int e = beg + t; e < end; e += 256){
    int d = get_dst(ei, is64, E, e);
    atomicAdd(&h[d >> 8], 1);
  }
  __syncthreads();
  block_counts[blk*256 + t] = h[t];
}

__global__ void p2_bucket_scan(const int* __restrict__ block_counts, int* __restrict__ bucket_base){
  __shared__ int sd[256];
  int t = threadIdx.x;
  int tot = 0;
  for (int b = 0; b < NBLK; ++b) tot += block_counts[b*256 + t];
  sd[t] = tot; __syncthreads();
  for (int off = 1; off < 256; off <<= 1){
    int v = (t >= off) ? sd[t - off] : 0;
    __syncthreads(); sd[t] += v; __syncthreads();
  }
  bucket_base[t] = sd[t] - tot;            // exclusive
  if (t == 255) bucket_base[256] = sd[255];
}

__global__ void p2_block_off(const int* __restrict__ block_counts, const int* __restrict__ bucket_base,
                             int* __restrict__ block_off){
  __shared__ int sd[256];
  int b = blockIdx.x, t = threadIdx.x;
  int v = block_counts[t*256 + b];
  sd[t] = v; __syncthreads();
  for (int off = 1; off < 256; off <<= 1){
    int u = (t >= off) ? sd[t - off] : 0;
    __syncthreads(); sd[t] += u; __syncthreads();
  }
  block_off[t*256 + b] = bucket_base[b] + sd[t] - v;
}

__global__ __launch_bounds__(256) void p3_scatter(const void* ei, const int* flag, int E, int E2,
                                                  const int* __restrict__ block_off,
                                                  int2* __restrict__ pairs){
  __shared__ int cur[256];
  int t = threadIdx.x, blk = blockIdx.x;
  cur[t] = block_off[blk*256 + t];
  __syncthreads();
  int chunk = (E2 + NBLK - 1)/NBLK;
  int beg = blk*chunk, end = min(beg + chunk, E2);
  int is64 = *flag;
  for (int e = beg + t; e < end; e += 256){
    int s, d; get_edge(ei, is64, E, e, s, d);
    int pos = atomicAdd(&cur[d >> 8], 1);
    pairs[pos] = make_int2(s, d);
  }
}

__global__ __launch_bounds__(256) void p4_sort(const int2* __restrict__ pairs,
                                               const int* __restrict__ bucket_base,
                                               int N, int E2,
                                               int* __restrict__ offs, int* __restrict__ srcs){
  __shared__ int hist[256];
  __shared__ int cur[256];
  int b = blockIdx.x, t = threadIdx.x;
  int base = bucket_base[b], cnt = bucket_base[b + 1] - base;
  hist[t] = 0; __syncthreads();
  for (int p = t; p < cnt; p += 256){
    int2 sd2 = pairs[base + p];
    atomicAdd(&hist[sd2.y & 255], 1);
  }
  __syncthreads();
  int v = hist[t];
  cur[t] = v; __syncthreads();
  for (int off = 1; off < 256; off <<= 1){
    int u = (t >= off) ? cur[t - off] : 0;
    __syncthreads(); cur[t] += u; __syncthreads();
  }
  int ex = cur[t] - v;   // exclusive prefix within bucket
  __syncthreads();
  cur[t] = ex;
  int node = b*256 + t;
  if (node < N) offs[node] = base + ex;
  __syncthreads();
  for (int p = t; p < cnt; p += 256){
    int2 sd2 = pairs[base + p];
    int pos = atomicAdd(&cur[sd2.y & 255], 1);
    srcs[base + pos] = sd2.x;
  }
  if (b == 0 && t == 0) offs[N] = E2;
}

// ---------------- node-parallel aggregation, multi-edge-per-wave ----------------
// agg_l1: 8 lane-groups of 8; group g handles edge p+g; lane c=lane&7 owns head c
// (cols 8c..8c+8 = uint4 of bf16). Weight computed in-kernel per (edge, head).
__global__ __launch_bounds__(256) void agg_l1(const char* __restrict__ h1b,
                       const float* __restrict__ asrc, const float* __restrict__ adst,
                       const int* __restrict__ offs, const int* __restrict__ srcs,
                       const float* __restrict__ bias, uint4* __restrict__ hout, int N){
  int tid = threadIdx.x;
  int i = blockIdx.x*4 + (tid >> 6);
  if (i >= N) return;
  int lane = tid & 63, g = lane >> 3, c = lane & 7;
  float ad = adst[i*8 + c];
  int beg = offs[i], end = offs[i + 1], last = end - 1;
  float acc[8];
#pragma unroll
  for (int k = 0; k < 8; ++k) acc[k] = 0.f;
  float den = 0.f;
  for (int p = beg; p < end; p += 16){
    int m0 = p + g, m1 = p + 8 + g;
    int i0 = min(m0, last), i1 = min(m1, last);
    int s0 = srcs[i0], s1 = srcs[i1];
    float a0 = asrc[s0*8 + c], a1 = asrc[s1*8 + c];
    uint4 v0 = *(const uint4*)(h1b + ((size_t)s0 << 7) + (c << 4));
    uint4 v1 = *(const uint4*)(h1b + ((size_t)s1 << 7) + (c << 4));
    float z0 = a0 + ad; z0 = (z0 >= 0.f) ? z0 : NEG_SLOPE*z0;
    float z1 = a1 + ad; z1 = (z1 >= 0.f) ? z1 : NEG_SLOPE*z1;
    float w0 = (m0 < end) ? __expf(z0) : 0.f;
    float w1 = (m1 < end) ? __expf(z1) : 0.f;
    den += w0 + w1;
    acc[0] = fmaf(w0, bf16lo(v0.x), acc[0]); acc[1] = fmaf(w0, bf16hi(v0.x), acc[1]);
    acc[2] = fmaf(w0, bf16lo(v0.y), acc[2]); acc[3] = fmaf(w0, bf16hi(v0.y), acc[3]);
    acc[4] = fmaf(w0, bf16lo(v0.z), acc[4]); acc[5] = fmaf(w0, bf16hi(v0.z), acc[5]);
    acc[6] = fmaf(w0, bf16lo(v0.w), acc[6]); acc[7] = fmaf(w0, bf16hi(v0.w), acc[7]);
    acc[0] = fmaf(w1, bf16lo(v1.x), acc[0]); acc[1] = fmaf(w1, bf16hi(v1.x), acc[1]);
    acc[2] = fmaf(w1, bf16lo(v1.y), acc[2]); acc[3] = fmaf(w1, bf16hi(v1.y), acc[3]);
    acc[4] = fmaf(w1, bf16lo(v1.z), acc[4]); acc[5] = fmaf(w1, bf16hi(v1.z), acc[5]);
    acc[6] = fmaf(w1, bf16lo(v1.w), acc[6]); acc[7] = fmaf(w1, bf16hi(v1.w), acc[7]);
  }
#pragma unroll
  for (int m = 8; m <= 32; m <<= 1){
#pragma unroll
    for (int k = 0; k < 8; ++k) acc[k] += __shfl_xor(acc[k], m, 64);
    den += __shfl_xor(den, m, 64);
  }
  if (g == 0){
    float inv = 1.f/(den + EPSV);
    unsigned pk[4];
#pragma unroll
    for (int k = 0; k < 4; ++k){
      float o0 = acc[2*k]*inv     + bias[c*8 + 2*k];
      float o1 = acc[2*k + 1]*inv + bias[c*8 + 2*k + 1];
      o0 = (o0 > 0.f) ? o0 : (__expf(o0) - 1.f);   // ELU fused
      o1 = (o1 > 0.f) ? o1 : (__expf(o1) - 1.f);
      pk[k] = (unsigned)(unsigned short)bf16r(o0) | ((unsigned)(unsigned short)bf16r(o1) << 16);
    }
    uint4 o; o.x = pk[0]; o.y = pk[1]; o.z = pk[2]; o.w = pk[3];
    hout[(size_t)i*8 + c] = o;
  }
}

// agg_l2: 4 lane-groups of 16; group g handles edge p+g; lane c=lane&15 owns cols 8c..8c+8.
__global__ __launch_bounds__(256) void agg_l2(const char* __restrict__ h2b,
                       const float* __restrict__ asrc, const float* __restrict__ adst,
                       const int* __restrict__ offs, const int* __restrict__ srcs,
                       const float* __restrict__ bias, float* __restrict__ out, int N){
  int tid = threadIdx.x;
  int i = blockIdx.x*4 + (tid >> 6);
  if (i >= N) return;
  int lane = tid & 63, g = lane >> 4, c = lane & 15;
  float ad = adst[i];
  int beg = offs[i], end = offs[i + 1], last = end - 1;
  float acc[8];
#pragma unroll
  for (int k = 0; k < 8; ++k) acc[k] = 0.f;
  float den = 0.f;
  for (int p = beg; p < end; p += 8){
    int m0 = p + g, m1 = p + 4 + g;
    int i0 = min(m0, last), i1 = min(m1, last);
    int s0 = srcs[i0], s1 = srcs[i1];
    float a0 = asrc[s0], a1 = asrc[s1];
    uint4 v0 = *(const uint4*)(h2b + ((size_t)s0 << 8) + (c << 4));
    uint4 v1 = *(const uint4*)(h2b + ((size_t)s1 << 8) + (c << 4));
    float z0 = a0 + ad; z0 = (z0 >= 0.f) ? z0 : NEG_SLOPE*z0;
    float z1 = a1 + ad; z1 = (z1 >= 0.f) ? z1 : NEG_SLOPE*z1;
    float w0 = (m0 < end) ? __expf(z0) : 0.f;
    float w1 = (m1 < end) ? __expf(z1) : 0.f;
    den += w0 + w1;
    acc[0] = fmaf(w0, bf16lo(v0.x), acc[0]); acc[1] = fmaf(w0, bf16hi(v0.x), acc[1]);
    acc[2] = fmaf(w0, bf16lo(v0.y), acc[2]); acc[3] = fmaf(w0, bf16hi(v0.y), acc[3]);
    acc[4] = fmaf(w0, bf16lo(v0.z), acc[4]); acc[5] = fmaf(w0, bf16hi(v0.z), acc[5]);
    acc[6] = fmaf(w0, bf16lo(v0.w), acc[6]); acc[7] = fmaf(w0, bf16hi(v0.w), acc[7]);
    acc[0] = fmaf(w1, bf16lo(v1.x), acc[0]); acc[1] = fmaf(w1, bf16hi(v1.x), acc[1]);
    acc[2] = fmaf(w1, bf16lo(v1.y), acc[2]); acc[3] = fmaf(w1, bf16hi(v1.y), acc[3]);
    acc[4] = fmaf(w1, bf16lo(v1.z), acc[4]); acc[5] = fmaf(w1, bf16hi(v1.z), acc[5]);
    acc[6] = fmaf(w1, bf16lo(v1.w), acc[6]); acc[7] = fmaf(w1, bf16hi(v1.w), acc[7]);
  }
#pragma unroll
  for (int m = 16; m <= 32; m <<= 1){
#pragma unroll
    for (int k = 0; k < 8; ++k) acc[k] += __shfl_xor(acc[k], m, 64);
    den += __shfl_xor(den, m, 64);
  }
  if (g == 0){
    float inv = 1.f/(den + EPSV);
    f32x4 o0, o1;
#pragma unroll
    for (int k = 0; k < 4; ++k) o0[k] = acc[k]*inv     + bias[c*8 + k];
#pragma unroll
    for (int k = 0; k < 4; ++k) o1[k] = acc[4 + k]*inv + bias[c*8 + 4 + k];
    *(f32x4*)(out + (size_t)i*128 + c*8)     = o0;
    *(f32x4*)(out + (size_t)i*128 + c*8 + 4) = o1;
  }
}

// ---------------- launch ----------------
extern "C" void kernel_launch(void* const* d_in, const int* in_sizes, int n_in,
                              void* d_out, int out_size, void* d_ws, size_t ws_size,
                              hipStream_t stream){
  const float* x   = (const float*)d_in[0];
  const void*  ei  = d_in[1];
  const float* W1  = (const float*)d_in[2];
  const float* as1 = (const float*)d_in[3];
  const float* ad1 = (const float*)d_in[4];
  const float* b1  = (const float*)d_in[5];
  const float* W2  = (const float*)d_in[6];
  const float* as2 = (const float*)d_in[7];
  const float* ad2 = (const float*)d_in[8];
  const float* b2  = (const float*)d_in[9];

  int N  = in_sizes[0] / 128;
  int E  = in_sizes[1] / 2;
  int E2 = E + N;
  int NB = (N + 255) >> 8;   // dst buckets of 256 nodes

  char* p = (char*)d_ws;
  auto alloc = [&](size_t bytes) -> void* {
    void* r = (void*)p;
    p += (bytes + 255) & ~(size_t)255;
    return r;
  };
  short* xb     = (short*)alloc((size_t)N*128*2);
  short* W1p    = (short*)alloc((size_t)128*64*2);
  short* W2p    = (short*)alloc((size_t)64*128*2);
  short* h1b    = (short*)alloc((size_t)N*64*2);
  float* asrc1  = (float*)alloc((size_t)N*8*4);
  float* adst1  = (float*)alloc((size_t)N*8*4);
  short* hin2   = (short*)alloc((size_t)N*64*2);
  short* h2b    = (short*)alloc((size_t)N*128*2);
  float* asrc2  = (float*)alloc((size_t)N*4);
  float* adst2  = (float*)alloc((size_t)N*4);
  int*   offs   = (int*)alloc((size_t)(N + 1)*4);
  int*   srcs   = (int*)alloc((size_t)E2*4);
  int2*  pairs  = (int2*)alloc((size_t)E2*8);
  int*   bcnt   = (int*)alloc((size_t)NBLK*256*4);
  int*   boff   = (int*)alloc((size_t)NBLK*256*4);
  int*   bbase  = (int*)alloc(257*4);
  int*   flag   = (int*)alloc(4);

  dim3 B(256);
  detect_dtype<<<1, 64, 0, stream>>>((const int*)ei, flag);

  int n4 = N*128/4;
  cvt_to_bf16<<<(n4 + 255)/256, B, 0, stream>>>(x, xb, n4);
  pack_w<<<(128*64 + 255)/256, B, 0, stream>>>(W1, W1p, 128, 64);
  pack_w<<<(64*128 + 255)/256, B, 0, stream>>>(W2, W2p, 64, 128);

  int nwav = (N + 15)/16;
  gemm_mfma<128,64><<<(nwav + 3)/4, B, 0, stream>>>(xb, W1p, h1b, N);
  logits_l1<<<(N + 3)/4, B, 0, stream>>>((const unsigned short*)h1b, as1, ad1, asrc1, adst1, N);

  // CSR by dst via two-level counting sort (reused by both layers)
  p1_hist<<<NBLK, B, 0, stream>>>(ei, flag, E, E2, bcnt);
  p2_bucket_scan<<<1, B, 0, stream>>>(bcnt, bbase);
  p2_block_off<<<256, B, 0, stream>>>(bcnt, bbase, boff);
  p3_scatter<<<NBLK, B, 0, stream>>>(ei, flag, E, E2, boff, pairs);
  p4_sort<<<NB, B, 0, stream>>>(pairs, bbase, N, E2, offs, srcs);

  agg_l1<<<(N + 3)/4, B, 0, stream>>>((const char*)h1b, asrc1, adst1, offs, srcs, b1,
                                      (uint4*)hin2, N);

  gemm_mfma<64,128><<<(nwav + 3)/4, B, 0, stream>>>(hin2, W2p, h2b, N);
  logits_l2<<<(N + 3)/4, B, 0, stream>>>((const unsigned*)h2b, as2, ad2, asrc2, adst2, N);
  agg_l2<<<(N + 3)/4, B, 0, stream>>>((const char*)h2b, asrc2, adst2, offs, srcs, b2,
                                      (float*)d_out, N);
}

// Round 7
// 276.301 us; speedup vs baseline: 1.1614x; 1.0231x over previous
//
#include <hip/hip_runtime.h>
#include <stdint.h>

#define NEG_SLOPE 0.2f
#define EPSV 1e-16f
#define NBLK 256   // scatter/histogram blocks (fixed, deterministic edge ranges)

typedef __attribute__((ext_vector_type(8))) short short8;
typedef __attribute__((ext_vector_type(4))) float f32x4;

// round-to-nearest-even fp32 -> bf16 bits
__device__ inline short bf16r(float f){
  union { float f; unsigned u; } v; v.f = f;
  unsigned r = (v.u + 0x7FFFu + ((v.u >> 16) & 1u)) >> 16;
  return (short)r;
}
__device__ inline float bf16lo(unsigned u){
  union { unsigned u; float f; } v; v.u = u << 16; return v.f;
}
__device__ inline float bf16hi(unsigned u){
  union { unsigned u; float f; } v; v.u = u & 0xFFFF0000u; return v.f;
}

// ---------------- edge access (int32 or int64 edge_index, [2,E] row-major) ----------------
__device__ inline void get_edge(const void* ei, int is64, int E, int e, int& s, int& d){
  if (e >= E){ s = d = e - E; return; }  // self loops appended
  if (is64){
    const long long* p = (const long long*)ei;
    s = (int)p[e]; d = (int)p[(long long)E + e];
  } else {
    const int* p = (const int*)ei;
    s = p[e]; d = p[E + e];
  }
}

__device__ inline int get_dst(const void* ei, int is64, int E, int e){
  if (e >= E) return e - E;
  if (is64) return (int)((const long long*)ei)[(long long)E + e];
  return ((const int*)ei)[E + e];
}

__global__ void detect_dtype(const int* ei32, int* flag){
  if (threadIdx.x == 0 && blockIdx.x == 0){
    int nz = 0;
    for (int i = 0; i < 64; ++i) nz |= ei32[2*i + 1];  // int64: high words all 0
    *flag = (nz == 0) ? 1 : 0;
  }
}

// ---------------- fp32 -> bf16 conversion (vectorized: 4 elems/thread) ----------------
__global__ void cvt_to_bf16(const float* __restrict__ x, short* __restrict__ xb, int n4){
  int i = blockIdx.x*blockDim.x + threadIdx.x;
  if (i >= n4) return;
  f32x4 v = *(const f32x4*)(x + (size_t)i*4);
  short4 o;
  o.x = bf16r(v[0]); o.y = bf16r(v[1]); o.z = bf16r(v[2]); o.w = bf16r(v[3]);
  *(short4*)(xb + (size_t)i*4) = o;
}

// ---------------- pack W1 and W2 (fused) fp32 -> per-fragment bf16 layout ----------------
__device__ inline void pack_one(const float* W, short* Wp, int NCOL, int idx){
  int NNT = NCOL >> 4;
  int j = idx & 7, n16 = (idx >> 3) & 15, q = (idx >> 7) & 3, tile = idx >> 9;
  int nt = tile % NNT, kt = tile / NNT;
  int k = kt*32 + q*8 + j, n = nt*16 + n16;
  Wp[idx] = bf16r(W[k*NCOL + n]);
}
__global__ void pack_w_both(const float* __restrict__ W1, short* __restrict__ W1p,
                            const float* __restrict__ W2, short* __restrict__ W2p){
  int idx = blockIdx.x*blockDim.x + threadIdx.x;   // 16384 total
  if (idx < 8192) pack_one(W1, W1p, 64, idx);
  else            pack_one(W2, W2p, 128, idx - 8192);
}

// ---------------- MFMA GEMM: Cb (bf16 out only) ----------------
template<int K, int NCOL>
__global__ __launch_bounds__(256) void gemm_mfma(const short* __restrict__ A, const short* __restrict__ Bp,
                                                 short* __restrict__ Cb, int M){
  constexpr int NKT = K/32, NNT = NCOL/16;
  int wave = (blockIdx.x*256 + (int)threadIdx.x) >> 6;
  int lane = threadIdx.x & 63;
  int row0 = wave << 4;
  if (row0 >= M) return;
  int m = lane & 15, q = lane >> 4;
  f32x4 acc[NNT];
#pragma unroll
  for (int i = 0; i < NNT; ++i) acc[i] = (f32x4){0.f,0.f,0.f,0.f};
#pragma unroll
  for (int kt = 0; kt < NKT; ++kt){
    short8 a = *(const short8*)(A + (size_t)(row0 + m)*K + kt*32 + q*8);
#pragma unroll
    for (int nt = 0; nt < NNT; ++nt){
      short8 b = *(const short8*)(Bp + (size_t)(((kt*NNT + nt)*4 + q)*16 + m)*8);
      acc[nt] = __builtin_amdgcn_mfma_f32_16x16x32_bf16(a, b, acc[nt], 0, 0, 0);
    }
  }
#pragma unroll
  for (int nt = 0; nt < NNT; ++nt){
#pragma unroll
    for (int r = 0; r < 4; ++r){
      Cb[(size_t)(row0 + q*4 + r)*NCOL + nt*16 + m] = bf16r(acc[nt][r]);
    }
  }
}

// ---------------- attention logit reductions (from bf16 h) ----------------
__global__ void logits_l1(const unsigned short* __restrict__ h1b, const float* __restrict__ att_s,
                          const float* __restrict__ att_d, float* __restrict__ asrc,
                          float* __restrict__ adst, int N){
  int tid = threadIdx.x;
  int n = blockIdx.x*4 + (tid >> 6);
  int j = tid & 63;
  if (n >= N) return;
  float h = bf16lo((unsigned)h1b[(size_t)n*64 + j]);
  float ps = h * att_s[j];
  float pd = h * att_d[j];
#pragma unroll
  for (int mm = 4; mm; mm >>= 1){ ps += __shfl_xor(ps, mm, 8); pd += __shfl_xor(pd, mm, 8); }
  if ((j & 7) == 0){ asrc[n*8 + (j >> 3)] = ps; adst[n*8 + (j >> 3)] = pd; }
}

__global__ void logits_l2(const unsigned* __restrict__ h2u, const float* __restrict__ att_s,
                          const float* __restrict__ att_d, float* __restrict__ asrc,
                          float* __restrict__ adst, int N){
  int tid = threadIdx.x;
  int n = blockIdx.x*4 + (tid >> 6);
  int l = tid & 63;
  if (n >= N) return;
  unsigned u = h2u[(size_t)n*64 + l];
  float x0 = bf16lo(u), x1 = bf16hi(u);
  float ps = x0*att_s[2*l] + x1*att_s[2*l + 1];
  float pd = x0*att_d[2*l] + x1*att_d[2*l + 1];
#pragma unroll
  for (int mm = 32; mm; mm >>= 1){ ps += __shfl_xor(ps, mm, 64); pd += __shfl_xor(pd, mm, 64); }
  if (l == 0){ asrc[n] = ps; adst[n] = pd; }
}

// ================= CSR build: two-level counting sort (no global atomics) =================
__global__ __launch_bounds__(256) void p1_hist(const void* ei, const int* flag, int E, int E2,
                                               int* __restrict__ block_counts){
  __shared__ int h[256];
  int t = threadIdx.x, blk = blockIdx.x;
  h[t] = 0; __syncthreads();
  int chunk = (E2 + NBLK - 1)/NBLK;
  int beg = blk*chunk, end = min(beg + chunk, E2);
  int is64 = *flag;
  for (int e = beg + t; e < end; e += 256){
    int d = get_dst(ei, is64, E, e);
    atomicAdd(&h[d >> 8], 1);
  }
  __syncthreads();
  block_counts[blk*256 + t] = h[t];
}

__global__ void p2_bucket_scan(const int* __restrict__ block_counts, int* __restrict__ bucket_base){
  __shared__ int sd[256];
  int t = threadIdx.x;
  int tot = 0;
  for (int b = 0; b < NBLK; ++b) tot += block_counts[b*256 + t];
  sd[t] = tot; __syncthreads();
  for (int off = 1; off < 256; off <<= 1){
    int v = (t >= off) ? sd[t - off] : 0;
    __syncthreads(); sd[t] += v; __syncthreads();
  }
  bucket_base[t] = sd[t] - tot;            // exclusive
  if (t == 255) bucket_base[256] = sd[255];
}

__global__ void p2_block_off(const int* __restrict__ block_counts, const int* __restrict__ bucket_base,
                             int* __restrict__ block_off){
  __shared__ int sd[256];
  int b = blockIdx.x, t = threadIdx.x;
  int v = block_counts[t*256 + b];
  sd[t] = v; __syncthreads();
  for (int off = 1; off < 256; off <<= 1){
    int u = (t >= off) ? sd[t - off] : 0;
    __syncthreads(); sd[t] += u; __syncthreads();
  }
  block_off[t*256 + b] = bucket_base[b] + sd[t] - v;
}

// P3: scatter packed (s<<8 | d&255) into bucket-major runs (4 B/edge; s < 2^24 assumed, N=50000)
__global__ __launch_bounds__(256) void p3_scatter(const void* ei, const int* flag, int E, int E2,
                                                  const int* __restrict__ block_off,
                                                  unsigned* __restrict__ packed){
  __shared__ int cur[256];
  int t = threadIdx.x, blk = blockIdx.x;
  cur[t] = block_off[blk*256 + t];
  __syncthreads();
  int chunk = (E2 + NBLK - 1)/NBLK;
  int beg = blk*chunk, end = min(beg + chunk, E2);
  int is64 = *flag;
  for (int e = beg + t; e < end; e += 256){
    int s, d; get_edge(ei, is64, E, e, s, d);
    int pos = atomicAdd(&cur[d >> 8], 1);
    packed[pos] = ((unsigned)s << 8) | (unsigned)(d & 255);
  }
}

__global__ __launch_bounds__(256) void p4_sort(const unsigned* __restrict__ packed,
                                               const int* __restrict__ bucket_base,
                                               int N, int E2,
                                               int* __restrict__ offs, int* __restrict__ srcs){
  __shared__ int hist[256];
  __shared__ int cur[256];
  int b = blockIdx.x, t = threadIdx.x;
  int base = bucket_base[b], cnt = bucket_base[b + 1] - base;
  hist[t] = 0; __syncthreads();
  for (int p = t; p < cnt; p += 256){
    atomicAdd(&hist[packed[base + p] & 255u], 1);
  }
  __syncthreads();
  int v = hist[t];
  cur[t] = v; __syncthreads();
  for (int off = 1; off < 256; off <<= 1){
    int u = (t >= off) ? cur[t - off] : 0;
    __syncthreads(); cur[t] += u; __syncthreads();
  }
  int ex = cur[t] - v;   // exclusive prefix within bucket
  __syncthreads();
  cur[t] = ex;
  int node = b*256 + t;
  if (node < N) offs[node] = base + ex;
  __syncthreads();
  for (int p = t; p < cnt; p += 256){
    unsigned pk = packed[base + p];
    int pos = atomicAdd(&cur[pk & 255u], 1);
    srcs[base + pos] = (int)(pk >> 8);
  }
  if (b == 0 && t == 0) offs[N] = E2;
}

// ---------------- node-parallel aggregation, multi-edge-per-wave, phase-batched ----------------
// agg_l1: 8 groups of 8 lanes; 4 slots/group/iter = 32 edges/iter; lane c owns head c (16 B).
__global__ __launch_bounds__(256) void agg_l1(const char* __restrict__ h1b,
                       const float* __restrict__ asrc, const float* __restrict__ adst,
                       const int* __restrict__ offs, const int* __restrict__ srcs,
                       const float* __restrict__ bias, uint4* __restrict__ hout, int N){
  int tid = threadIdx.x;
  int i = blockIdx.x*4 + (tid >> 6);
  if (i >= N) return;
  int lane = tid & 63, g = lane >> 3, c = lane & 7;
  float ad = adst[i*8 + c];
  int beg = offs[i], end = offs[i + 1], last = end - 1;
  float acc[8];
#pragma unroll
  for (int k = 0; k < 8; ++k) acc[k] = 0.f;
  float den = 0.f;
  for (int p = beg; p < end; p += 32){
    int m[4], s[4];
#pragma unroll
    for (int k = 0; k < 4; ++k) m[k] = p + 8*k + g;
#pragma unroll
    for (int k = 0; k < 4; ++k) s[k] = srcs[min(m[k], last)];
    float a[4];
#pragma unroll
    for (int k = 0; k < 4; ++k) a[k] = asrc[s[k]*8 + c];
    uint4 v[4];
#pragma unroll
    for (int k = 0; k < 4; ++k) v[k] = *(const uint4*)(h1b + ((size_t)s[k] << 7) + (c << 4));
    float w[4];
#pragma unroll
    for (int k = 0; k < 4; ++k){
      float z = a[k] + ad; z = (z >= 0.f) ? z : NEG_SLOPE*z;
      w[k] = (m[k] < end) ? __expf(z) : 0.f;
      den += w[k];
    }
#pragma unroll
    for (int k = 0; k < 4; ++k){
      acc[0] = fmaf(w[k], bf16lo(v[k].x), acc[0]); acc[1] = fmaf(w[k], bf16hi(v[k].x), acc[1]);
      acc[2] = fmaf(w[k], bf16lo(v[k].y), acc[2]); acc[3] = fmaf(w[k], bf16hi(v[k].y), acc[3]);
      acc[4] = fmaf(w[k], bf16lo(v[k].z), acc[4]); acc[5] = fmaf(w[k], bf16hi(v[k].z), acc[5]);
      acc[6] = fmaf(w[k], bf16lo(v[k].w), acc[6]); acc[7] = fmaf(w[k], bf16hi(v[k].w), acc[7]);
    }
  }
#pragma unroll
  for (int mm = 8; mm <= 32; mm <<= 1){
#pragma unroll
    for (int k = 0; k < 8; ++k) acc[k] += __shfl_xor(acc[k], mm, 64);
    den += __shfl_xor(den, mm, 64);
  }
  if (g == 0){
    float inv = 1.f/(den + EPSV);
    unsigned pk[4];
#pragma unroll
    for (int k = 0; k < 4; ++k){
      float o0 = acc[2*k]*inv     + bias[c*8 + 2*k];
      float o1 = acc[2*k + 1]*inv + bias[c*8 + 2*k + 1];
      o0 = (o0 > 0.f) ? o0 : (__expf(o0) - 1.f);   // ELU fused
      o1 = (o1 > 0.f) ? o1 : (__expf(o1) - 1.f);
      pk[k] = (unsigned)(unsigned short)bf16r(o0) | ((unsigned)(unsigned short)bf16r(o1) << 16);
    }
    uint4 o; o.x = pk[0]; o.y = pk[1]; o.z = pk[2]; o.w = pk[3];
    hout[(size_t)i*8 + c] = o;
  }
}

// agg_l2: 4 groups of 16 lanes; 4 slots/group/iter = 16 edges/iter; lane c owns cols 8c..8c+8.
__global__ __launch_bounds__(256) void agg_l2(const char* __restrict__ h2b,
                       const float* __restrict__ asrc, const float* __restrict__ adst,
                       const int* __restrict__ offs, const int* __restrict__ srcs,
                       const float* __restrict__ bias, float* __restrict__ out, int N){
  int tid = threadIdx.x;
  int i = blockIdx.x*4 + (tid >> 6);
  if (i >= N) return;
  int lane = tid & 63, g = lane >> 4, c = lane & 15;
  float ad = adst[i];
  int beg = offs[i], end = offs[i + 1], last = end - 1;
  float acc[8];
#pragma unroll
  for (int k = 0; k < 8; ++k) acc[k] = 0.f;
  float den = 0.f;
  for (int p = beg; p < end; p += 16){
    int m[4], s[4];
#pragma unroll
    for (int k = 0; k < 4; ++k) m[k] = p + 4*k + g;
#pragma unroll
    for (int k = 0; k < 4; ++k) s[k] = srcs[min(m[k], last)];
    float a[4];
#pragma unroll
    for (int k = 0; k < 4; ++k) a[k] = asrc[s[k]];
    uint4 v[4];
#pragma unroll
    for (int k = 0; k < 4; ++k) v[k] = *(const uint4*)(h2b + ((size_t)s[k] << 8) + (c << 4));
    float w[4];
#pragma unroll
    for (int k = 0; k < 4; ++k){
      float z = a[k] + ad; z = (z >= 0.f) ? z : NEG_SLOPE*z;
      w[k] = (m[k] < end) ? __expf(z) : 0.f;
      den += w[k];
    }
#pragma unroll
    for (int k = 0; k < 4; ++k){
      acc[0] = fmaf(w[k], bf16lo(v[k].x), acc[0]); acc[1] = fmaf(w[k], bf16hi(v[k].x), acc[1]);
      acc[2] = fmaf(w[k], bf16lo(v[k].y), acc[2]); acc[3] = fmaf(w[k], bf16hi(v[k].y), acc[3]);
      acc[4] = fmaf(w[k], bf16lo(v[k].z), acc[4]); acc[5] = fmaf(w[k], bf16hi(v[k].z), acc[5]);
      acc[6] = fmaf(w[k], bf16lo(v[k].w), acc[6]); acc[7] = fmaf(w[k], bf16hi(v[k].w), acc[7]);
    }
  }
#pragma unroll
  for (int mm = 16; mm <= 32; mm <<= 1){
#pragma unroll
    for (int k = 0; k < 8; ++k) acc[k] += __shfl_xor(acc[k], mm, 64);
    den += __shfl_xor(den, mm, 64);
  }
  if (g == 0){
    float inv = 1.f/(den + EPSV);
    f32x4 o0, o1;
#pragma unroll
    for (int k = 0; k < 4; ++k) o0[k] = acc[k]*inv     + bias[c*8 + k];
#pragma unroll
    for (int k = 0; k < 4; ++k) o1[k] = acc[4 + k]*inv + bias[c*8 + 4 + k];
    *(f32x4*)(out + (size_t)i*128 + c*8)     = o0;
    *(f32x4*)(out + (size_t)i*128 + c*8 + 4) = o1;
  }
}

// ---------------- launch ----------------
extern "C" void kernel_launch(void* const* d_in, const int* in_sizes, int n_in,
                              void* d_out, int out_size, void* d_ws, size_t ws_size,
                              hipStream_t stream){
  const float* x   = (const float*)d_in[0];
  const void*  ei  = d_in[1];
  const float* W1  = (const float*)d_in[2];
  const float* as1 = (const float*)d_in[3];
  const float* ad1 = (const float*)d_in[4];
  const float* b1  = (const float*)d_in[5];
  const float* W2  = (const float*)d_in[6];
  const float* as2 = (const float*)d_in[7];
  const float* ad2 = (const float*)d_in[8];
  const float* b2  = (const float*)d_in[9];

  int N  = in_sizes[0] / 128;
  int E  = in_sizes[1] / 2;
  int E2 = E + N;
  int NB = (N + 255) >> 8;   // dst buckets of 256 nodes

  char* p = (char*)d_ws;
  auto alloc = [&](size_t bytes) -> void* {
    void* r = (void*)p;
    p += (bytes + 255) & ~(size_t)255;
    return r;
  };
  short*    xb     = (short*)alloc((size_t)N*128*2);
  short*    W1p    = (short*)alloc((size_t)128*64*2);
  short*    W2p    = (short*)alloc((size_t)64*128*2);
  short*    h1b    = (short*)alloc((size_t)N*64*2);
  float*    asrc1  = (float*)alloc((size_t)N*8*4);
  float*    adst1  = (float*)alloc((size_t)N*8*4);
  short*    hin2   = (short*)alloc((size_t)N*64*2);
  short*    h2b    = (short*)alloc((size_t)N*128*2);
  float*    asrc2  = (float*)alloc((size_t)N*4);
  float*    adst2  = (float*)alloc((size_t)N*4);
  int*      offs   = (int*)alloc((size_t)(N + 1)*4);
  int*      srcs   = (int*)alloc((size_t)E2*4);
  unsigned* packed = (unsigned*)alloc((size_t)E2*4);
  int*      bcnt   = (int*)alloc((size_t)NBLK*256*4);
  int*      boff   = (int*)alloc((size_t)NBLK*256*4);
  int*      bbase  = (int*)alloc(257*4);
  int*      flag   = (int*)alloc(4);

  dim3 B(256);
  detect_dtype<<<1, 64, 0, stream>>>((const int*)ei, flag);

  int n4 = N*128/4;
  cvt_to_bf16<<<(n4 + 255)/256, B, 0, stream>>>(x, xb, n4);
  pack_w_both<<<16384/256, B, 0, stream>>>(W1, W1p, W2, W2p);

  int nwav = (N + 15)/16;
  gemm_mfma<128,64><<<(nwav + 3)/4, B, 0, stream>>>(xb, W1p, h1b, N);
  logits_l1<<<(N + 3)/4, B, 0, stream>>>((const unsigned short*)h1b, as1, ad1, asrc1, adst1, N);

  // CSR by dst via two-level counting sort (reused by both layers)
  p1_hist<<<NBLK, B, 0, stream>>>(ei, flag, E, E2, bcnt);
  p2_bucket_scan<<<1, B, 0, stream>>>(bcnt, bbase);
  p2_block_off<<<256, B, 0, stream>>>(bcnt, bbase, boff);
  p3_scatter<<<NBLK, B, 0, stream>>>(ei, flag, E, E2, boff, packed);
  p4_sort<<<NB, B, 0, stream>>>(packed, bbase, N, E2, offs, srcs);

  agg_l1<<<(N + 3)/4, B, 0, stream>>>((const char*)h1b, asrc1, adst1, offs, srcs, b1,
                                      (uint4*)hin2, N);

  gemm_mfma<64,128><<<(nwav + 3)/4, B, 0, stream>>>(hin2, W2p, h2b, N);
  logits_l2<<<(N + 3)/4, B, 0, stream>>>((const unsigned*)h2b, as2, ad2, asrc2, adst2, N);
  agg_l2<<<(N + 3)/4, B, 0, stream>>>((const char*)h2b, asrc2, adst2, offs, srcs, b2,
                                      (float*)d_out, N);
}

// Round 8
// 254.240 us; speedup vs baseline: 1.2622x; 1.0868x over previous
//
#include <hip/hip_runtime.h>
#include <stdint.h>

#define NEG_SLOPE 0.2f
#define EPSV 1e-16f
#define NBLK 256   // scatter/histogram blocks (fixed, deterministic edge ranges)

typedef __attribute__((ext_vector_type(8))) short short8;
typedef __attribute__((ext_vector_type(4))) float f32x4;

// round-to-nearest-even fp32 -> bf16 bits
__device__ inline short bf16r(float f){
  union { float f; unsigned u; } v; v.f = f;
  unsigned r = (v.u + 0x7FFFu + ((v.u >> 16) & 1u)) >> 16;
  return (short)r;
}
__device__ inline float bf16lo(unsigned u){
  union { unsigned u; float f; } v; v.u = u << 16; return v.f;
}
__device__ inline float bf16hi(unsigned u){
  union { unsigned u; float f; } v; v.u = u & 0xFFFF0000u; return v.f;
}

// ---------------- edge access (int32 or int64 edge_index, [2,E] row-major) ----------------
__device__ inline void get_edge(const void* ei, int is64, int E, int e, int& s, int& d){
  if (e >= E){ s = d = e - E; return; }  // self loops appended
  if (is64){
    const long long* p = (const long long*)ei;
    s = (int)p[e]; d = (int)p[(long long)E + e];
  } else {
    const int* p = (const int*)ei;
    s = p[e]; d = p[E + e];
  }
}

__device__ inline int get_dst(const void* ei, int is64, int E, int e){
  if (e >= E) return e - E;
  if (is64) return (int)((const long long*)ei)[(long long)E + e];
  return ((const int*)ei)[E + e];
}

__global__ void detect_dtype(const int* ei32, int* flag){
  if (threadIdx.x == 0 && blockIdx.x == 0){
    int nz = 0;
    for (int i = 0; i < 64; ++i) nz |= ei32[2*i + 1];  // int64: high words all 0
    *flag = (nz == 0) ? 1 : 0;
  }
}

// ---------------- fp32 -> bf16 conversion (vectorized: 4 elems/thread) ----------------
__global__ void cvt_to_bf16(const float* __restrict__ x, short* __restrict__ xb, int n4){
  int i = blockIdx.x*blockDim.x + threadIdx.x;
  if (i >= n4) return;
  f32x4 v = *(const f32x4*)(x + (size_t)i*4);
  short4 o;
  o.x = bf16r(v[0]); o.y = bf16r(v[1]); o.z = bf16r(v[2]); o.w = bf16r(v[3]);
  *(short4*)(xb + (size_t)i*4) = o;
}

// ---------------- pack W1 and W2 (fused) fp32 -> per-fragment bf16 layout ----------------
__device__ inline void pack_one(const float* W, short* Wp, int NCOL, int idx){
  int NNT = NCOL >> 4;
  int j = idx & 7, n16 = (idx >> 3) & 15, q = (idx >> 7) & 3, tile = idx >> 9;
  int nt = tile % NNT, kt = tile / NNT;
  int k = kt*32 + q*8 + j, n = nt*16 + n16;
  Wp[idx] = bf16r(W[k*NCOL + n]);
}
__global__ void pack_w_both(const float* __restrict__ W1, short* __restrict__ W1p,
                            const float* __restrict__ W2, short* __restrict__ W2p){
  int idx = blockIdx.x*blockDim.x + threadIdx.x;   // 16384 total
  if (idx < 8192) pack_one(W1, W1p, 64, idx);
  else            pack_one(W2, W2p, 128, idx - 8192);
}

// ---------------- va = W2 @ att2 : [64] vectors so layer-2 logits come from hin2 ----------------
__global__ void gemv_att2(const float* __restrict__ W2, const float* __restrict__ as2,
                          const float* __restrict__ ad2, float* __restrict__ va_s,
                          float* __restrict__ va_d){
  int k = threadIdx.x;   // 64 threads
  float s = 0.f, d = 0.f;
  for (int c = 0; c < 128; ++c){
    float w = W2[k*128 + c];
    s = fmaf(w, as2[c], s);
    d = fmaf(w, ad2[c], d);
  }
  va_s[k] = s; va_d[k] = d;
}

// ---------------- MFMA GEMM: Cb (bf16 out) ----------------
template<int K, int NCOL>
__global__ __launch_bounds__(256) void gemm_mfma(const short* __restrict__ A, const short* __restrict__ Bp,
                                                 short* __restrict__ Cb, int M){
  constexpr int NKT = K/32, NNT = NCOL/16;
  int wave = (blockIdx.x*256 + (int)threadIdx.x) >> 6;
  int lane = threadIdx.x & 63;
  int row0 = wave << 4;
  if (row0 >= M) return;
  int m = lane & 15, q = lane >> 4;
  f32x4 acc[NNT];
#pragma unroll
  for (int i = 0; i < NNT; ++i) acc[i] = (f32x4){0.f,0.f,0.f,0.f};
#pragma unroll
  for (int kt = 0; kt < NKT; ++kt){
    short8 a = *(const short8*)(A + (size_t)(row0 + m)*K + kt*32 + q*8);
#pragma unroll
    for (int nt = 0; nt < NNT; ++nt){
      short8 b = *(const short8*)(Bp + (size_t)(((kt*NNT + nt)*4 + q)*16 + m)*8);
      acc[nt] = __builtin_amdgcn_mfma_f32_16x16x32_bf16(a, b, acc[nt], 0, 0, 0);
    }
  }
#pragma unroll
  for (int nt = 0; nt < NNT; ++nt){
#pragma unroll
    for (int r = 0; r < 4; ++r){
      Cb[(size_t)(row0 + q*4 + r)*NCOL + nt*16 + m] = bf16r(acc[nt][r]);
    }
  }
}

// ---------------- MFMA GEMM with bias, fp32 out (final layer) ----------------
template<int K, int NCOL>
__global__ __launch_bounds__(256) void gemm_mfma_bias(const short* __restrict__ A, const short* __restrict__ Bp,
                                                      const float* __restrict__ bias,
                                                      float* __restrict__ C, int M){
  constexpr int NKT = K/32, NNT = NCOL/16;
  int wave = (blockIdx.x*256 + (int)threadIdx.x) >> 6;
  int lane = threadIdx.x & 63;
  int row0 = wave << 4;
  if (row0 >= M) return;
  int m = lane & 15, q = lane >> 4;
  f32x4 acc[NNT];
#pragma unroll
  for (int i = 0; i < NNT; ++i) acc[i] = (f32x4){0.f,0.f,0.f,0.f};
#pragma unroll
  for (int kt = 0; kt < NKT; ++kt){
    short8 a = *(const short8*)(A + (size_t)(row0 + m)*K + kt*32 + q*8);
#pragma unroll
    for (int nt = 0; nt < NNT; ++nt){
      short8 b = *(const short8*)(Bp + (size_t)(((kt*NNT + nt)*4 + q)*16 + m)*8);
      acc[nt] = __builtin_amdgcn_mfma_f32_16x16x32_bf16(a, b, acc[nt], 0, 0, 0);
    }
  }
#pragma unroll
  for (int nt = 0; nt < NNT; ++nt){
    float bv = bias[nt*16 + m];
#pragma unroll
    for (int r = 0; r < 4; ++r){
      C[(size_t)(row0 + q*4 + r)*NCOL + nt*16 + m] = acc[nt][r] + bv;
    }
  }
}

// ---------------- layer-1 logit reduction (from bf16 h1) ----------------
__global__ void logits_l1(const unsigned short* __restrict__ h1b, const float* __restrict__ att_s,
                          const float* __restrict__ att_d, float* __restrict__ asrc,
                          float* __restrict__ adst, int N){
  int tid = threadIdx.x;
  int n = blockIdx.x*4 + (tid >> 6);
  int j = tid & 63;
  if (n >= N) return;
  float h = bf16lo((unsigned)h1b[(size_t)n*64 + j]);
  float ps = h * att_s[j];
  float pd = h * att_d[j];
#pragma unroll
  for (int mm = 4; mm; mm >>= 1){ ps += __shfl_xor(ps, mm, 8); pd += __shfl_xor(pd, mm, 8); }
  if ((j & 7) == 0){ asrc[n*8 + (j >> 3)] = ps; adst[n*8 + (j >> 3)] = pd; }
}

// ================= CSR build: two-level counting sort (no global atomics) =================
__global__ __launch_bounds__(256) void p1_hist(const void* ei, const int* flag, int E, int E2,
                                               int* __restrict__ block_counts){
  __shared__ int h[256];
  int t = threadIdx.x, blk = blockIdx.x;
  h[t] = 0; __syncthreads();
  int chunk = (E2 + NBLK - 1)/NBLK;
  int beg = blk*chunk, end = min(beg + chunk, E2);
  int is64 = *flag;
  for (int e = beg + t; e < end; e += 256){
    int d = get_dst(ei, is64, E, e);
    atomicAdd(&h[d >> 8], 1);
  }
  __syncthreads();
  block_counts[blk*256 + t] = h[t];
}

__global__ void p2_bucket_scan(const int* __restrict__ block_counts, int* __restrict__ bucket_base){
  __shared__ int sd[256];
  int t = threadIdx.x;
  int tot = 0;
  for (int b = 0; b < NBLK; ++b) tot += block_counts[b*256 + t];
  sd[t] = tot; __syncthreads();
  for (int off = 1; off < 256; off <<= 1){
    int v = (t >= off) ? sd[t - off] : 0;
    __syncthreads(); sd[t] += v; __syncthreads();
  }
  bucket_base[t] = sd[t] - tot;            // exclusive
  if (t == 255) bucket_base[256] = sd[255];
}

__global__ void p2_block_off(const int* __restrict__ block_counts, const int* __restrict__ bucket_base,
                             int* __restrict__ block_off){
  __shared__ int sd[256];
  int b = blockIdx.x, t = threadIdx.x;
  int v = block_counts[t*256 + b];
  sd[t] = v; __syncthreads();
  for (int off = 1; off < 256; off <<= 1){
    int u = (t >= off) ? sd[t - off] : 0;
    __syncthreads(); sd[t] += u; __syncthreads();
  }
  block_off[t*256 + b] = bucket_base[b] + sd[t] - v;
}

// P3: scatter packed (s<<8 | d&255) into bucket-major runs (4 B/edge; s < 2^24, N=50000)
__global__ __launch_bounds__(256) void p3_scatter(const void* ei, const int* flag, int E, int E2,
                                                  const int* __restrict__ block_off,
                                                  unsigned* __restrict__ packed){
  __shared__ int cur[256];
  int t = threadIdx.x, blk = blockIdx.x;
  cur[t] = block_off[blk*256 + t];
  __syncthreads();
  int chunk = (E2 + NBLK - 1)/NBLK;
  int beg = blk*chunk, end = min(beg + chunk, E2);
  int is64 = *flag;
  for (int e = beg + t; e < end; e += 256){
    int s, d; get_edge(ei, is64, E, e, s, d);
    int pos = atomicAdd(&cur[d >> 8], 1);
    packed[pos] = ((unsigned)s << 8) | (unsigned)(d & 255);
  }
}

__global__ __launch_bounds__(256) void p4_sort(const unsigned* __restrict__ packed,
                                               const int* __restrict__ bucket_base,
                                               int N, int E2,
                                               int* __restrict__ offs, int* __restrict__ srcs){
  __shared__ int hist[256];
  __shared__ int cur[256];
  int b = blockIdx.x, t = threadIdx.x;
  int base = bucket_base[b], cnt = bucket_base[b + 1] - base;
  hist[t] = 0; __syncthreads();
  for (int p = t; p < cnt; p += 256){
    atomicAdd(&hist[packed[base + p] & 255u], 1);
  }
  __syncthreads();
  int v = hist[t];
  cur[t] = v; __syncthreads();
  for (int off = 1; off < 256; off <<= 1){
    int u = (t >= off) ? cur[t - off] : 0;
    __syncthreads(); cur[t] += u; __syncthreads();
  }
  int ex = cur[t] - v;   // exclusive prefix within bucket
  __syncthreads();
  cur[t] = ex;
  int node = b*256 + t;
  if (node < N) offs[node] = base + ex;
  __syncthreads();
  for (int p = t; p < cnt; p += 256){
    unsigned pk = packed[base + p];
    int pos = atomicAdd(&cur[pk & 255u], 1);
    srcs[base + pos] = (int)(pk >> 8);
  }
  if (b == 0 && t == 0) offs[N] = E2;
}

// ---------------- layer-1 aggregation + fused ELU + fused layer-2 logits ----------------
// 8 groups of 8 lanes; 4 slots/group/iter = 32 edges/iter; lane c owns head c (16 B of row).
__global__ __launch_bounds__(256) void agg_l1(const char* __restrict__ h1b,
                       const float* __restrict__ asrc, const float* __restrict__ adst,
                       const int* __restrict__ offs, const int* __restrict__ srcs,
                       const float* __restrict__ bias,
                       const float* __restrict__ va_s, const float* __restrict__ va_d,
                       uint4* __restrict__ hout,
                       float* __restrict__ asrc2, float* __restrict__ adst2, int N){
  int tid = threadIdx.x;
  int i = blockIdx.x*4 + (tid >> 6);
  if (i >= N) return;
  int lane = tid & 63, g = lane >> 3, c = lane & 7;
  float ad = adst[i*8 + c];
  int beg = offs[i], end = offs[i + 1], last = end - 1;
  float acc[8];
#pragma unroll
  for (int k = 0; k < 8; ++k) acc[k] = 0.f;
  float den = 0.f;
  for (int p = beg; p < end; p += 32){
    int m[4], s[4];
#pragma unroll
    for (int k = 0; k < 4; ++k) m[k] = p + 8*k + g;
#pragma unroll
    for (int k = 0; k < 4; ++k) s[k] = srcs[min(m[k], last)];
    float a[4];
#pragma unroll
    for (int k = 0; k < 4; ++k) a[k] = asrc[s[k]*8 + c];
    uint4 v[4];
#pragma unroll
    for (int k = 0; k < 4; ++k) v[k] = *(const uint4*)(h1b + ((size_t)s[k] << 7) + (c << 4));
    float w[4];
#pragma unroll
    for (int k = 0; k < 4; ++k){
      float z = a[k] + ad; z = (z >= 0.f) ? z : NEG_SLOPE*z;
      w[k] = (m[k] < end) ? __expf(z) : 0.f;
      den += w[k];
    }
#pragma unroll
    for (int k = 0; k < 4; ++k){
      acc[0] = fmaf(w[k], bf16lo(v[k].x), acc[0]); acc[1] = fmaf(w[k], bf16hi(v[k].x), acc[1]);
      acc[2] = fmaf(w[k], bf16lo(v[k].y), acc[2]); acc[3] = fmaf(w[k], bf16hi(v[k].y), acc[3]);
      acc[4] = fmaf(w[k], bf16lo(v[k].z), acc[4]); acc[5] = fmaf(w[k], bf16hi(v[k].z), acc[5]);
      acc[6] = fmaf(w[k], bf16lo(v[k].w), acc[6]); acc[7] = fmaf(w[k], bf16hi(v[k].w), acc[7]);
    }
  }
#pragma unroll
  for (int mm = 8; mm <= 32; mm <<= 1){
#pragma unroll
    for (int k = 0; k < 8; ++k) acc[k] += __shfl_xor(acc[k], mm, 64);
    den += __shfl_xor(den, mm, 64);
  }
  if (g == 0){
    float inv = 1.f/(den + EPSV);
    float o[8];
#pragma unroll
    for (int k = 0; k < 8; ++k){
      float t = acc[k]*inv + bias[c*8 + k];
      o[k] = (t > 0.f) ? t : (__expf(t) - 1.f);   // ELU fused
    }
    unsigned pk[4];
#pragma unroll
    for (int k = 0; k < 4; ++k)
      pk[k] = (unsigned)(unsigned short)bf16r(o[2*k]) | ((unsigned)(unsigned short)bf16r(o[2*k+1]) << 16);
    uint4 ov; ov.x = pk[0]; ov.y = pk[1]; ov.z = pk[2]; ov.w = pk[3];
    hout[(size_t)i*8 + c] = ov;
    // fused layer-2 logits: asrc2[i] = hin2[i] . va_s, adst2[i] = hin2[i] . va_d
    float ps = 0.f, pd = 0.f;
#pragma unroll
    for (int k = 0; k < 8; ++k){
      ps = fmaf(o[k], va_s[c*8 + k], ps);
      pd = fmaf(o[k], va_d[c*8 + k], pd);
    }
#pragma unroll
    for (int mm = 1; mm <= 4; mm <<= 1){
      ps += __shfl_xor(ps, mm, 8);
      pd += __shfl_xor(pd, mm, 8);
    }
    if (c == 0){ asrc2[i] = ps; adst2[i] = pd; }
  }
}

// ---------------- layer-2 aggregation over hin2 (64 bf16 cols; GEMM applied AFTER) ----------------
// 8 groups of 8 lanes; 4 slots/group/iter = 32 edges/iter; lane c owns cols 8c..8c+8 (16 B).
__global__ __launch_bounds__(256) void agg_l2(const char* __restrict__ hin2,
                       const float* __restrict__ asrc, const float* __restrict__ adst,
                       const int* __restrict__ offs, const int* __restrict__ srcs,
                       uint4* __restrict__ qout, int N){
  int tid = threadIdx.x;
  int i = blockIdx.x*4 + (tid >> 6);
  if (i >= N) return;
  int lane = tid & 63, g = lane >> 3, c = lane & 7;
  float ad = adst[i];
  int beg = offs[i], end = offs[i + 1], last = end - 1;
  float acc[8];
#pragma unroll
  for (int k = 0; k < 8; ++k) acc[k] = 0.f;
  float den = 0.f;
  for (int p = beg; p < end; p += 32){
    int m[4], s[4];
#pragma unroll
    for (int k = 0; k < 4; ++k) m[k] = p + 8*k + g;
#pragma unroll
    for (int k = 0; k < 4; ++k) s[k] = srcs[min(m[k], last)];
    float a[4];
#pragma unroll
    for (int k = 0; k < 4; ++k) a[k] = asrc[s[k]];
    uint4 v[4];
#pragma unroll
    for (int k = 0; k < 4; ++k) v[k] = *(const uint4*)(hin2 + ((size_t)s[k] << 7) + (c << 4));
    float w[4];
#pragma unroll
    for (int k = 0; k < 4; ++k){
      float z = a[k] + ad; z = (z >= 0.f) ? z : NEG_SLOPE*z;
      w[k] = (m[k] < end) ? __expf(z) : 0.f;
      den += w[k];
    }
#pragma unroll
    for (int k = 0; k < 4; ++k){
      acc[0] = fmaf(w[k], bf16lo(v[k].x), acc[0]); acc[1] = fmaf(w[k], bf16hi(v[k].x), acc[1]);
      acc[2] = fmaf(w[k], bf16lo(v[k].y), acc[2]); acc[3] = fmaf(w[k], bf16hi(v[k].y), acc[3]);
      acc[4] = fmaf(w[k], bf16lo(v[k].z), acc[4]); acc[5] = fmaf(w[k], bf16hi(v[k].z), acc[5]);
      acc[6] = fmaf(w[k], bf16lo(v[k].w), acc[6]); acc[7] = fmaf(w[k], bf16hi(v[k].w), acc[7]);
    }
  }
#pragma unroll
  for (int mm = 8; mm <= 32; mm <<= 1){
#pragma unroll
    for (int k = 0; k < 8; ++k) acc[k] += __shfl_xor(acc[k], mm, 64);
    den += __shfl_xor(den, mm, 64);
  }
  if (g == 0){
    float inv = 1.f/(den + EPSV);
    unsigned pk[4];
#pragma unroll
    for (int k = 0; k < 4; ++k){
      float o0 = acc[2*k]*inv, o1 = acc[2*k + 1]*inv;
      pk[k] = (unsigned)(unsigned short)bf16r(o0) | ((unsigned)(unsigned short)bf16r(o1) << 16);
    }
    uint4 ov; ov.x = pk[0]; ov.y = pk[1]; ov.z = pk[2]; ov.w = pk[3];
    qout[(size_t)i*8 + c] = ov;
  }
}

// ---------------- launch ----------------
extern "C" void kernel_launch(void* const* d_in, const int* in_sizes, int n_in,
                              void* d_out, int out_size, void* d_ws, size_t ws_size,
                              hipStream_t stream){
  const float* x   = (const float*)d_in[0];
  const void*  ei  = d_in[1];
  const float* W1  = (const float*)d_in[2];
  const float* as1 = (const float*)d_in[3];
  const float* ad1 = (const float*)d_in[4];
  const float* b1  = (const float*)d_in[5];
  const float* W2  = (const float*)d_in[6];
  const float* as2 = (const float*)d_in[7];
  const float* ad2 = (const float*)d_in[8];
  const float* b2  = (const float*)d_in[9];

  int N  = in_sizes[0] / 128;
  int E  = in_sizes[1] / 2;
  int E2 = E + N;
  int NB = (N + 255) >> 8;   // dst buckets of 256 nodes

  char* p = (char*)d_ws;
  auto alloc = [&](size_t bytes) -> void* {
    void* r = (void*)p;
    p += (bytes + 255) & ~(size_t)255;
    return r;
  };
  short*    xb     = (short*)alloc((size_t)N*128*2);
  short*    W1p    = (short*)alloc((size_t)128*64*2);
  short*    W2p    = (short*)alloc((size_t)64*128*2);
  short*    h1b    = (short*)alloc((size_t)N*64*2);
  float*    asrc1  = (float*)alloc((size_t)N*8*4);
  float*    adst1  = (float*)alloc((size_t)N*8*4);
  short*    hin2   = (short*)alloc((size_t)N*64*2);
  short*    hq     = (short*)alloc((size_t)N*64*2);
  float*    asrc2  = (float*)alloc((size_t)N*4);
  float*    adst2  = (float*)alloc((size_t)N*4);
  float*    va_s2  = (float*)alloc(64*4);
  float*    va_d2  = (float*)alloc(64*4);
  int*      offs   = (int*)alloc((size_t)(N + 1)*4);
  int*      srcs   = (int*)alloc((size_t)E2*4);
  unsigned* packed = (unsigned*)alloc((size_t)E2*4);
  int*      bcnt   = (int*)alloc((size_t)NBLK*256*4);
  int*      boff   = (int*)alloc((size_t)NBLK*256*4);
  int*      bbase  = (int*)alloc(257*4);
  int*      flag   = (int*)alloc(4);

  dim3 B(256);
  detect_dtype<<<1, 64, 0, stream>>>((const int*)ei, flag);

  int n4 = N*128/4;
  cvt_to_bf16<<<(n4 + 255)/256, B, 0, stream>>>(x, xb, n4);
  pack_w_both<<<16384/256, B, 0, stream>>>(W1, W1p, W2, W2p);
  gemv_att2<<<1, 64, 0, stream>>>(W2, as2, ad2, va_s2, va_d2);

  int nwav = (N + 15)/16;
  gemm_mfma<128,64><<<(nwav + 3)/4, B, 0, stream>>>(xb, W1p, h1b, N);
  logits_l1<<<(N + 3)/4, B, 0, stream>>>((const unsigned short*)h1b, as1, ad1, asrc1, adst1, N);

  // CSR by dst via two-level counting sort (reused by both layers)
  p1_hist<<<NBLK, B, 0, stream>>>(ei, flag, E, E2, bcnt);
  p2_bucket_scan<<<1, B, 0, stream>>>(bcnt, bbase);
  p2_block_off<<<256, B, 0, stream>>>(bcnt, bbase, boff);
  p3_scatter<<<NBLK, B, 0, stream>>>(ei, flag, E, E2, boff, packed);
  p4_sort<<<NB, B, 0, stream>>>(packed, bbase, N, E2, offs, srcs);

  agg_l1<<<(N + 3)/4, B, 0, stream>>>((const char*)h1b, asrc1, adst1, offs, srcs, b1,
                                      va_s2, va_d2, (uint4*)hin2, asrc2, adst2, N);

  agg_l2<<<(N + 3)/4, B, 0, stream>>>((const char*)hin2, asrc2, adst2, offs, srcs,
                                      (uint4*)hq, N);

  gemm_mfma_bias<64,128><<<(nwav + 3)/4, B, 0, stream>>>(hq, W2p, b2, (float*)d_out, N);
}

// Round 9
// 243.046 us; speedup vs baseline: 1.3203x; 1.0461x over previous
//
#include <hip/hip_runtime.h>
#include <stdint.h>

#define NEG_SLOPE 0.2f
#define EPSV 1e-16f
#define LOG2E 1.44269504088896340736f
#define NBLK 256   // scatter/histogram blocks (fixed, deterministic edge ranges)

typedef __attribute__((ext_vector_type(8))) short short8;
typedef __attribute__((ext_vector_type(4))) float f32x4;

// round-to-nearest-even fp32 -> bf16 bits
__device__ inline short bf16r(float f){
  union { float f; unsigned u; } v; v.f = f;
  unsigned r = (v.u + 0x7FFFu + ((v.u >> 16) & 1u)) >> 16;
  return (short)r;
}
__device__ inline float bf16lo(unsigned u){
  union { unsigned u; float f; } v; v.u = u << 16; return v.f;
}
__device__ inline float bf16hi(unsigned u){
  union { unsigned u; float f; } v; v.u = u & 0xFFFF0000u; return v.f;
}

// ---------------- edge access (int32 or int64 edge_index, [2,E] row-major) ----------------
__device__ inline void get_edge(const void* ei, int is64, int E, int e, int& s, int& d){
  if (e >= E){ s = d = e - E; return; }  // self loops appended
  if (is64){
    const long long* p = (const long long*)ei;
    s = (int)p[e]; d = (int)p[(long long)E + e];
  } else {
    const int* p = (const int*)ei;
    s = p[e]; d = p[E + e];
  }
}

__device__ inline int get_dst(const void* ei, int is64, int E, int e){
  if (e >= E) return e - E;
  if (is64) return (int)((const long long*)ei)[(long long)E + e];
  return ((const int*)ei)[E + e];
}

// ---------------- prep: detect dtype + pack W1/W2 + gemv att2 (one kernel) ----------------
__device__ inline void pack_one(const float* W, short* Wp, int NCOL, int idx){
  int NNT = NCOL >> 4;
  int j = idx & 7, n16 = (idx >> 3) & 15, q = (idx >> 7) & 3, tile = idx >> 9;
  int nt = tile % NNT, kt = tile / NNT;
  int k = kt*32 + q*8 + j, n = nt*16 + n16;
  Wp[idx] = bf16r(W[k*NCOL + n]);
}
__global__ void prep(const int* __restrict__ ei32, int* __restrict__ flag,
                     const float* __restrict__ W1, short* __restrict__ W1p,
                     const float* __restrict__ W2, short* __restrict__ W2p,
                     const float* __restrict__ as2, const float* __restrict__ ad2,
                     float* __restrict__ va_s, float* __restrict__ va_d){
  int b = blockIdx.x, t = threadIdx.x;
  if (b < 64){
    int idx = b*256 + t;                 // 16384 total
    if (idx < 8192) pack_one(W1, W1p, 64, idx);
    else            pack_one(W2, W2p, 128, idx - 8192);
  } else {
    if (t == 0){
      int nz = 0;
      for (int i = 0; i < 64; ++i) nz |= ei32[2*i + 1];  // int64: high words all 0
      *flag = (nz == 0) ? 1 : 0;
    }
    if (t < 64){
      float s = 0.f, d = 0.f;
      for (int c = 0; c < 128; ++c){
        float w = W2[t*128 + c];
        s = fmaf(w, as2[c], s);
        d = fmaf(w, ad2[c], d);
      }
      va_s[t] = s * LOG2E; va_d[t] = d * LOG2E;   // pre-scaled for exp2
    }
  }
}

// ---------------- GEMM1 (fp32 x input, bf16 out) + fused layer-1 logits (x LOG2E) ----------------
__global__ __launch_bounds__(256) void gemm1(const float* __restrict__ x, const short* __restrict__ Bp,
                                             const float* __restrict__ att_s, const float* __restrict__ att_d,
                                             short* __restrict__ Cb,
                                             float* __restrict__ asrc1, float* __restrict__ adst1, int M){
  constexpr int NKT = 4, NNT = 4;      // K=128, NCOL=64
  int wave = (blockIdx.x*256 + (int)threadIdx.x) >> 6;
  int lane = threadIdx.x & 63;
  int row0 = wave << 4;
  if (row0 >= M) return;
  int m = lane & 15, q = lane >> 4;
  f32x4 acc[NNT];
#pragma unroll
  for (int i = 0; i < NNT; ++i) acc[i] = (f32x4){0.f,0.f,0.f,0.f};
#pragma unroll
  for (int kt = 0; kt < NKT; ++kt){
    const float* xr = x + (size_t)(row0 + m)*128 + kt*32 + q*8;
    f32x4 f0 = *(const f32x4*)xr;
    f32x4 f1 = *(const f32x4*)(xr + 4);
    short8 a;
#pragma unroll
    for (int j = 0; j < 4; ++j){ a[j] = bf16r(f0[j]); a[4 + j] = bf16r(f1[j]); }
#pragma unroll
    for (int nt = 0; nt < NNT; ++nt){
      short8 b = *(const short8*)(Bp + (size_t)(((kt*NNT + nt)*4 + q)*16 + m)*8);
      acc[nt] = __builtin_amdgcn_mfma_f32_16x16x32_bf16(a, b, acc[nt], 0, 0, 0);
    }
  }
  // store bf16 h1
#pragma unroll
  for (int nt = 0; nt < NNT; ++nt){
#pragma unroll
    for (int r = 0; r < 4; ++r){
      Cb[(size_t)(row0 + q*4 + r)*64 + nt*16 + m] = bf16r(acc[nt][r]);
    }
  }
  // fused logits: head = 2*nt + (m>>3); octet = m&7; scaled by LOG2E
  float atts[4], attd[4];
#pragma unroll
  for (int nt = 0; nt < 4; ++nt){
    atts[nt] = att_s[nt*16 + m] * LOG2E;
    attd[nt] = att_d[nt*16 + m] * LOG2E;
  }
  int isw = (m & 7) == 0;
#pragma unroll
  for (int r = 0; r < 4; ++r){
    int row = row0 + q*4 + r;
#pragma unroll
    for (int nt = 0; nt < 4; ++nt){
      float ps = acc[nt][r] * atts[nt];
      float pd = acc[nt][r] * attd[nt];
#pragma unroll
      for (int mm = 1; mm <= 4; mm <<= 1){
        ps += __shfl_xor(ps, mm, 64);
        pd += __shfl_xor(pd, mm, 64);
      }
      if (isw){
        int head = 2*nt + (m >> 3);
        asrc1[row*8 + head] = ps;
        adst1[row*8 + head] = pd;
      }
    }
  }
}

// ---------------- GEMM2 with bias, fp32 out (final layer) ----------------
__global__ __launch_bounds__(256) void gemm2(const short* __restrict__ A, const short* __restrict__ Bp,
                                             const float* __restrict__ bias,
                                             float* __restrict__ C, int M){
  constexpr int NKT = 2, NNT = 8;      // K=64, NCOL=128
  int wave = (blockIdx.x*256 + (int)threadIdx.x) >> 6;
  int lane = threadIdx.x & 63;
  int row0 = wave << 4;
  if (row0 >= M) return;
  int m = lane & 15, q = lane >> 4;
  f32x4 acc[NNT];
#pragma unroll
  for (int i = 0; i < NNT; ++i) acc[i] = (f32x4){0.f,0.f,0.f,0.f};
#pragma unroll
  for (int kt = 0; kt < NKT; ++kt){
    short8 a = *(const short8*)(A + (size_t)(row0 + m)*64 + kt*32 + q*8);
#pragma unroll
    for (int nt = 0; nt < NNT; ++nt){
      short8 b = *(const short8*)(Bp + (size_t)(((kt*NNT + nt)*4 + q)*16 + m)*8);
      acc[nt] = __builtin_amdgcn_mfma_f32_16x16x32_bf16(a, b, acc[nt], 0, 0, 0);
    }
  }
#pragma unroll
  for (int nt = 0; nt < NNT; ++nt){
    float bv = bias[nt*16 + m];
#pragma unroll
    for (int r = 0; r < 4; ++r){
      C[(size_t)(row0 + q*4 + r)*128 + nt*16 + m] = acc[nt][r] + bv;
    }
  }
}

// ================= CSR build: two-level counting sort (no global atomics) =================
__global__ __launch_bounds__(256) void p1_hist(const void* ei, const int* flag, int E, int E2,
                                               int* __restrict__ block_counts){
  __shared__ int h[256];
  int t = threadIdx.x, blk = blockIdx.x;
  h[t] = 0; __syncthreads();
  int chunk = (E2 + NBLK - 1)/NBLK;
  int beg = blk*chunk, end = min(beg + chunk, E2);
  int is64 = *flag;
  for (int e = beg + t; e < end; e += 256){
    int d = get_dst(ei, is64, E, e);
    atomicAdd(&h[d >> 8], 1);
  }
  __syncthreads();
  block_counts[blk*256 + t] = h[t];
}

// merged p2: grid=256 blocks, block b handles bucket b; block 0 also publishes bucket_base
__global__ __launch_bounds__(256) void p2_scan(const int* __restrict__ block_counts,
                                               int* __restrict__ bucket_base,
                                               int* __restrict__ block_off){
  __shared__ int tot[256];
  __shared__ int ex[256];
  __shared__ int col[256];
  int b = blockIdx.x, t = threadIdx.x;
  // bucket totals (thread t -> bucket t)
  int s = 0;
  for (int w = 0; w < NBLK; ++w) s += block_counts[w*256 + t];
  tot[t] = s; __syncthreads();
  // inclusive scan of totals
  for (int off = 1; off < 256; off <<= 1){
    int v = (t >= off) ? tot[t - off] : 0;
    __syncthreads(); tot[t] += v; __syncthreads();
  }
  ex[t] = tot[t] - s;        // exclusive bucket base
  __syncthreads();
  if (b == 0){
    bucket_base[t] = ex[t];
    if (t == 255) bucket_base[256] = tot[255];
  }
  int base = ex[b];
  // per-writer-block offsets for bucket b
  int v = block_counts[t*256 + b];
  col[t] = v; __syncthreads();
  for (int off = 1; off < 256; off <<= 1){
    int u = (t >= off) ? col[t - off] : 0;
    __syncthreads(); col[t] += u; __syncthreads();
  }
  block_off[t*256 + b] = base + col[t] - v;
}

// P3: scatter packed (s<<8 | d&255) into bucket-major runs (4 B/edge; s < 2^24, N=50000)
__global__ __launch_bounds__(256) void p3_scatter(const void* ei, const int* flag, int E, int E2,
                                                  const int* __restrict__ block_off,
                                                  unsigned* __restrict__ packed){
  __shared__ int cur[256];
  int t = threadIdx.x, blk = blockIdx.x;
  cur[t] = block_off[blk*256 + t];
  __syncthreads();
  int chunk = (E2 + NBLK - 1)/NBLK;
  int beg = blk*chunk, end = min(beg + chunk, E2);
  int is64 = *flag;
  for (int e = beg + t; e < end; e += 256){
    int s, d; get_edge(ei, is64, E, e, s, d);
    int pos = atomicAdd(&cur[d >> 8], 1);
    packed[pos] = ((unsigned)s << 8) | (unsigned)(d & 255);
  }
}

// P4: in-bucket counting sort; srcs stored as BYTE offsets (s*128) for 32-bit gather addressing
__global__ __launch_bounds__(256) void p4_sort(const unsigned* __restrict__ packed,
                                               const int* __restrict__ bucket_base,
                                               int N, int E2,
                                               int* __restrict__ offs, int* __restrict__ srcs){
  __shared__ int hist[256];
  __shared__ int cur[256];
  int b = blockIdx.x, t = threadIdx.x;
  int base = bucket_base[b], cnt = bucket_base[b + 1] - base;
  hist[t] = 0; __syncthreads();
  for (int p = t; p < cnt; p += 256){
    atomicAdd(&hist[packed[base + p] & 255u], 1);
  }
  __syncthreads();
  int v = hist[t];
  cur[t] = v; __syncthreads();
  for (int off = 1; off < 256; off <<= 1){
    int u = (t >= off) ? cur[t - off] : 0;
    __syncthreads(); cur[t] += u; __syncthreads();
  }
  int ex = cur[t] - v;   // exclusive prefix within bucket
  __syncthreads();
  cur[t] = ex;
  int node = b*256 + t;
  if (node < N) offs[node] = base + ex;
  __syncthreads();
  for (int p = t; p < cnt; p += 256){
    unsigned pk = packed[base + p];
    int pos = atomicAdd(&cur[pk & 255u], 1);
    srcs[base + pos] = (int)((pk >> 8) << 7);   // byte offset s*128
  }
  if (b == 0 && t == 0) offs[N] = E2;
}

// ---------------- layer-1 aggregation + fused ELU + fused layer-2 logits ----------------
// logits pre-scaled by LOG2E -> weights via exp2f. srcs[] holds byte offsets (s*128).
__global__ __launch_bounds__(256) void agg_l1(const char* __restrict__ h1b,
                       const float* __restrict__ asrc, const float* __restrict__ adst,
                       const int* __restrict__ offs, const int* __restrict__ srcs,
                       const float* __restrict__ bias,
                       const float* __restrict__ va_s, const float* __restrict__ va_d,
                       uint4* __restrict__ hout,
                       float* __restrict__ asrc2, float* __restrict__ adst2, int N){
  int tid = threadIdx.x;
  int i = blockIdx.x*4 + (tid >> 6);
  if (i >= N) return;
  int lane = tid & 63, g = lane >> 3, c = lane & 7;
  unsigned coff = (unsigned)(c << 4);
  float ad = adst[i*8 + c];
  int beg = offs[i], end = offs[i + 1], last = end - 1;
  float acc[8];
#pragma unroll
  for (int k = 0; k < 8; ++k) acc[k] = 0.f;
  float den = 0.f;
  for (int p = beg; p < end; p += 32){
    int m[4]; unsigned so[4];
#pragma unroll
    for (int k = 0; k < 4; ++k) m[k] = p + 8*k + g;
#pragma unroll
    for (int k = 0; k < 4; ++k) so[k] = (unsigned)srcs[min(m[k], last)];
    float a[4];
#pragma unroll
    for (int k = 0; k < 4; ++k) a[k] = asrc[(so[k] >> 4) + (unsigned)c];
    uint4 v[4];
#pragma unroll
    for (int k = 0; k < 4; ++k) v[k] = *(const uint4*)(h1b + (size_t)(so[k] + coff));
    float w[4];
#pragma unroll
    for (int k = 0; k < 4; ++k){
      float z = a[k] + ad;
      z = fmaxf(z, NEG_SLOPE*z);           // leaky-relu (scale-commuting form)
      w[k] = (m[k] < end) ? exp2f(z) : 0.f;
      den += w[k];
    }
#pragma unroll
    for (int k = 0; k < 4; ++k){
      acc[0] = fmaf(w[k], bf16lo(v[k].x), acc[0]); acc[1] = fmaf(w[k], bf16hi(v[k].x), acc[1]);
      acc[2] = fmaf(w[k], bf16lo(v[k].y), acc[2]); acc[3] = fmaf(w[k], bf16hi(v[k].y), acc[3]);
      acc[4] = fmaf(w[k], bf16lo(v[k].z), acc[4]); acc[5] = fmaf(w[k], bf16hi(v[k].z), acc[5]);
      acc[6] = fmaf(w[k], bf16lo(v[k].w), acc[6]); acc[7] = fmaf(w[k], bf16hi(v[k].w), acc[7]);
    }
  }
#pragma unroll
  for (int mm = 8; mm <= 32; mm <<= 1){
#pragma unroll
    for (int k = 0; k < 8; ++k) acc[k] += __shfl_xor(acc[k], mm, 64);
    den += __shfl_xor(den, mm, 64);
  }
  if (g == 0){
    float inv = 1.f/(den + EPSV);
    float o[8];
#pragma unroll
    for (int k = 0; k < 8; ++k){
      float t = acc[k]*inv + bias[c*8 + k];
      o[k] = (t > 0.f) ? t : (__expf(t) - 1.f);   // ELU fused
    }
    unsigned pk[4];
#pragma unroll
    for (int k = 0; k < 4; ++k)
      pk[k] = (unsigned)(unsigned short)bf16r(o[2*k]) | ((unsigned)(unsigned short)bf16r(o[2*k+1]) << 16);
    uint4 ov; ov.x = pk[0]; ov.y = pk[1]; ov.z = pk[2]; ov.w = pk[3];
    hout[(size_t)i*8 + c] = ov;
    // fused layer-2 logits (va pre-scaled by LOG2E)
    float ps = 0.f, pd = 0.f;
#pragma unroll
    for (int k = 0; k < 8; ++k){
      ps = fmaf(o[k], va_s[c*8 + k], ps);
      pd = fmaf(o[k], va_d[c*8 + k], pd);
    }
#pragma unroll
    for (int mm = 1; mm <= 4; mm <<= 1){
      ps += __shfl_xor(ps, mm, 8);
      pd += __shfl_xor(pd, mm, 8);
    }
    if (c == 0){ asrc2[i] = ps; adst2[i] = pd; }
  }
}

// ---------------- layer-2 aggregation over hin2 (64 bf16 cols; GEMM applied AFTER) ----------------
__global__ __launch_bounds__(256) void agg_l2(const char* __restrict__ hin2,
                       const float* __restrict__ asrc, const float* __restrict__ adst,
                       const int* __restrict__ offs, const int* __restrict__ srcs,
                       uint4* __restrict__ qout, int N){
  int tid = threadIdx.x;
  int i = blockIdx.x*4 + (tid >> 6);
  if (i >= N) return;
  int lane = tid & 63, g = lane >> 3, c = lane & 7;
  unsigned coff = (unsigned)(c << 4);
  float ad = adst[i];
  int beg = offs[i], end = offs[i + 1], last = end - 1;
  float acc[8];
#pragma unroll
  for (int k = 0; k < 8; ++k) acc[k] = 0.f;
  float den = 0.f;
  for (int p = beg; p < end; p += 32){
    int m[4]; unsigned so[4];
#pragma unroll
    for (int k = 0; k < 4; ++k) m[k] = p + 8*k + g;
#pragma unroll
    for (int k = 0; k < 4; ++k) so[k] = (unsigned)srcs[min(m[k], last)];
    float a[4];
#pragma unroll
    for (int k = 0; k < 4; ++k) a[k] = asrc[so[k] >> 7];
    uint4 v[4];
#pragma unroll
    for (int k = 0; k < 4; ++k) v[k] = *(const uint4*)(hin2 + (size_t)(so[k] + coff));
    float w[4];
#pragma unroll
    for (int k = 0; k < 4; ++k){
      float z = a[k] + ad;
      z = fmaxf(z, NEG_SLOPE*z);
      w[k] = (m[k] < end) ? exp2f(z) : 0.f;
      den += w[k];
    }
#pragma unroll
    for (int k = 0; k < 4; ++k){
      acc[0] = fmaf(w[k], bf16lo(v[k].x), acc[0]); acc[1] = fmaf(w[k], bf16hi(v[k].x), acc[1]);
      acc[2] = fmaf(w[k], bf16lo(v[k].y), acc[2]); acc[3] = fmaf(w[k], bf16hi(v[k].y), acc[3]);
      acc[4] = fmaf(w[k], bf16lo(v[k].z), acc[4]); acc[5] = fmaf(w[k], bf16hi(v[k].z), acc[5]);
      acc[6] = fmaf(w[k], bf16lo(v[k].w), acc[6]); acc[7] = fmaf(w[k], bf16hi(v[k].w), acc[7]);
    }
  }
#pragma unroll
  for (int mm = 8; mm <= 32; mm <<= 1){
#pragma unroll
    for (int k = 0; k < 8; ++k) acc[k] += __shfl_xor(acc[k], mm, 64);
    den += __shfl_xor(den, mm, 64);
  }
  if (g == 0){
    float inv = 1.f/(den + EPSV);
    unsigned pk[4];
#pragma unroll
    for (int k = 0; k < 4; ++k){
      float o0 = acc[2*k]*inv, o1 = acc[2*k + 1]*inv;
      pk[k] = (unsigned)(unsigned short)bf16r(o0) | ((unsigned)(unsigned short)bf16r(o1) << 16);
    }
    uint4 ov; ov.x = pk[0]; ov.y = pk[1]; ov.z = pk[2]; ov.w = pk[3];
    qout[(size_t)i*8 + c] = ov;
  }
}

// ---------------- launch ----------------
extern "C" void kernel_launch(void* const* d_in, const int* in_sizes, int n_in,
                              void* d_out, int out_size, void* d_ws, size_t ws_size,
                              hipStream_t stream){
  const float* x   = (const float*)d_in[0];
  const void*  ei  = d_in[1];
  const float* W1  = (const float*)d_in[2];
  const float* as1 = (const float*)d_in[3];
  const float* ad1 = (const float*)d_in[4];
  const float* b1  = (const float*)d_in[5];
  const float* W2  = (const float*)d_in[6];
  const float* as2 = (const float*)d_in[7];
  const float* ad2 = (const float*)d_in[8];
  const float* b2  = (const float*)d_in[9];

  int N  = in_sizes[0] / 128;
  int E  = in_sizes[1] / 2;
  int E2 = E + N;
  int NB = (N + 255) >> 8;   // dst buckets of 256 nodes

  char* p = (char*)d_ws;
  auto alloc = [&](size_t bytes) -> void* {
    void* r = (void*)p;
    p += (bytes + 255) & ~(size_t)255;
    return r;
  };
  short*    W1p    = (short*)alloc((size_t)128*64*2);
  short*    W2p    = (short*)alloc((size_t)64*128*2);
  short*    h1b    = (short*)alloc((size_t)N*64*2);
  float*    asrc1  = (float*)alloc((size_t)N*8*4);
  float*    adst1  = (float*)alloc((size_t)N*8*4);
  short*    hin2   = (short*)alloc((size_t)N*64*2);
  short*    hq     = (short*)alloc((size_t)N*64*2);
  float*    asrc2  = (float*)alloc((size_t)N*4);
  float*    adst2  = (float*)alloc((size_t)N*4);
  float*    va_s2  = (float*)alloc(64*4);
  float*    va_d2  = (float*)alloc(64*4);
  int*      offs   = (int*)alloc((size_t)(N + 1)*4);
  int*      srcs   = (int*)alloc((size_t)E2*4);
  unsigned* packed = (unsigned*)alloc((size_t)E2*4);
  int*      bcnt   = (int*)alloc((size_t)NBLK*256*4);
  int*      boff   = (int*)alloc((size_t)NBLK*256*4);
  int*      bbase  = (int*)alloc(257*4);
  int*      flag   = (int*)alloc(4);

  dim3 B(256);
  prep<<<65, B, 0, stream>>>((const int*)ei, flag, W1, W1p, W2, W2p, as2, ad2, va_s2, va_d2);

  int nwav = (N + 15)/16;
  gemm1<<<(nwav + 3)/4, B, 0, stream>>>(x, W1p, as1, ad1, h1b, asrc1, adst1, N);

  // CSR by dst via two-level counting sort (reused by both layers)
  p1_hist<<<NBLK, B, 0, stream>>>(ei, flag, E, E2, bcnt);
  p2_scan<<<256, B, 0, stream>>>(bcnt, bbase, boff);
  p3_scatter<<<NBLK, B, 0, stream>>>(ei, flag, E, E2, boff, packed);
  p4_sort<<<NB, B, 0, stream>>>(packed, bbase, N, E2, offs, srcs);

  agg_l1<<<(N + 3)/4, B, 0, stream>>>((const char*)h1b, asrc1, adst1, offs, srcs, b1,
                                      va_s2, va_d2, (uint4*)hin2, asrc2, adst2, N);

  agg_l2<<<(N + 3)/4, B, 0, stream>>>((const char*)hin2, asrc2, adst2, offs, srcs,
                                      (uint4*)hq, N);

  gemm2<<<(nwav + 3)/4, B, 0, stream>>>(hq, W2p, b2, (float*)d_out, N);
}